// Round 1
// baseline (688.408 us; speedup 1.0000x reference)
//
#include <hip/hip_runtime.h>
#include <math.h>

#define N_NODES 50000
#define N_EDGES 800000
#define IN_DIM 128
#define HID 512
#define OUT_DIM 40

__global__ void zero_ints(int* __restrict__ a, int n) {
    int i = blockIdx.x * blockDim.x + threadIdx.x;
    if (i < n) a[i] = 0;
}

__global__ void count_deg(const int* __restrict__ dst, int* __restrict__ deg) {
    int e = blockIdx.x * blockDim.x + threadIdx.x;
    if (e < N_EDGES) atomicAdd(&deg[dst[e]], 1);
}

// single-block exclusive scan over 50000 degrees -> row_ptr[50001]
__global__ void scan_deg(const int* __restrict__ deg, int* __restrict__ row_ptr) {
    __shared__ int sums[1024];
    const int n = N_NODES;
    int tid = threadIdx.x;
    int chunk = (n + 1023) >> 10;  // 49
    int start = tid * chunk;
    int end = start + chunk; if (end > n) end = n;
    int s = 0;
    for (int i = start; i < end; ++i) s += deg[i];
    sums[tid] = s;
    __syncthreads();
    for (int off = 1; off < 1024; off <<= 1) {
        int add = (tid >= off) ? sums[tid - off] : 0;
        __syncthreads();
        sums[tid] += add;
        __syncthreads();
    }
    int base = sums[tid] - s;  // exclusive prefix
    for (int i = start; i < end; ++i) { row_ptr[i] = base; base += deg[i]; }
    if (tid == 1023) row_ptr[n] = sums[1023];
}

__global__ void fill_csr(const int* __restrict__ src, const int* __restrict__ dst,
                         const int* __restrict__ row_ptr, int* __restrict__ cursor,
                         int* __restrict__ csr_src) {
    int e = blockIdx.x * blockDim.x + threadIdx.x;
    if (e < N_EDGES) {
        int d = dst[e];
        int pos = atomicAdd(&cursor[d], 1);
        csr_src[row_ptr[d] + pos] = src[e];
    }
}

// one wave per node: mean of x[src] rows (128 feats, float2/lane)
__global__ void agg_x(const float* __restrict__ x, const int* __restrict__ row_ptr,
                      const int* __restrict__ csr_src, float* __restrict__ agg) {
    int wid = threadIdx.x >> 6;
    int lane = threadIdx.x & 63;
    int n = blockIdx.x * 4 + wid;
    if (n >= N_NODES) return;
    int beg = row_ptr[n], end = row_ptr[n + 1];
    float ax = 0.f, ay = 0.f;
    for (int e = beg; e < end; ++e) {
        int s = csr_src[e];
        float2 v = *(const float2*)(x + (size_t)s * IN_DIM + lane * 2);
        ax += v.x; ay += v.y;
    }
    int d = end - beg; if (d < 1) d = 1;
    float inv = 1.0f / (float)d;
    float2 o; o.x = ax * inv; o.y = ay * inv;
    *(float2*)(agg + (size_t)n * IN_DIM + lane * 2) = o;
}

// h = relu(agg @ w_l + x @ w_r + b)   [50000,128]x[128,512] twice, fused
__global__ __launch_bounds__(256) void gemm1(
    const float* __restrict__ agg, const float* __restrict__ x,
    const float* __restrict__ w_l, const float* __restrict__ w_r,
    const float* __restrict__ bias, float* __restrict__ h) {
    __shared__ float As1[32][64];  // [k][row] transposed
    __shared__ float As2[32][64];
    __shared__ float Bs1[32][64];  // [k][col]
    __shared__ float Bs2[32][64];
    int tid = threadIdx.x;
    int row0 = blockIdx.x * 64;
    int col0 = blockIdx.y * 64;
    int tx = tid & 15, ty = tid >> 4;
    float acc[4][4] = {};
    for (int kk = 0; kk < 128; kk += 32) {
        #pragma unroll
        for (int i = 0; i < 2; ++i) {
            int v = tid + i * 256;        // 512 float4 per A matrix
            int arow = v >> 3;
            int kq = v & 7;
            int grow = row0 + arow;
            float4 ga = {0, 0, 0, 0}, gx = {0, 0, 0, 0};
            if (grow < N_NODES) {
                ga = *(const float4*)(agg + (size_t)grow * 128 + kk + kq * 4);
                gx = *(const float4*)(x   + (size_t)grow * 128 + kk + kq * 4);
            }
            #pragma unroll
            for (int j = 0; j < 4; ++j) {
                As1[kq * 4 + j][arow] = ((const float*)&ga)[j];
                As2[kq * 4 + j][arow] = ((const float*)&gx)[j];
            }
        }
        #pragma unroll
        for (int i = 0; i < 2; ++i) {
            int v = tid + i * 256;        // 512 float4 per B matrix
            int k = v >> 4;
            int cq = v & 15;
            float4 gl = *(const float4*)(w_l + (size_t)(kk + k) * 512 + col0 + cq * 4);
            float4 gr = *(const float4*)(w_r + (size_t)(kk + k) * 512 + col0 + cq * 4);
            *(float4*)&Bs1[k][cq * 4] = gl;
            *(float4*)&Bs2[k][cq * 4] = gr;
        }
        __syncthreads();
        #pragma unroll
        for (int k = 0; k < 32; ++k) {
            float4 a1 = *(const float4*)&As1[k][ty * 4];
            float4 a2 = *(const float4*)&As2[k][ty * 4];
            float4 b1 = *(const float4*)&Bs1[k][tx * 4];
            float4 b2 = *(const float4*)&Bs2[k][tx * 4];
            #pragma unroll
            for (int i = 0; i < 4; ++i) {
                float a1i = ((const float*)&a1)[i];
                float a2i = ((const float*)&a2)[i];
                #pragma unroll
                for (int j = 0; j < 4; ++j) {
                    acc[i][j] += a1i * ((const float*)&b1)[j] + a2i * ((const float*)&b2)[j];
                }
            }
        }
        __syncthreads();
    }
    #pragma unroll
    for (int i = 0; i < 4; ++i) {
        int grow = row0 + ty * 4 + i;
        if (grow >= N_NODES) continue;
        float4 o;
        #pragma unroll
        for (int j = 0; j < 4; ++j) {
            float v = acc[i][j] + bias[col0 + tx * 4 + j];
            ((float*)&o)[j] = v > 0.f ? v : 0.f;
        }
        *(float4*)(h + (size_t)grow * 512 + col0 + tx * 4) = o;
    }
}

// p = h @ w2_l ; r = h @ w2_r    [50000,512]x[512,40] both in one pass over h
__global__ __launch_bounds__(256) void gemm2(
    const float* __restrict__ h, const float* __restrict__ w_l,
    const float* __restrict__ w_r, float* __restrict__ p, float* __restrict__ r) {
    __shared__ float Hs[64][133];   // pad 133 (odd): conflict-free Hs[lane][k] reads
    __shared__ float Ws[128][80];   // [k][0..39]=w_l row, [40..79]=w_r row
    int tid = threadIdx.x;
    int r0 = blockIdx.x * 64;
    int lane = tid & 63;
    int cg = tid >> 6;              // wave id -> 20-col group
    float acc[20] = {};
    for (int kk = 0; kk < 512; kk += 128) {
        #pragma unroll
        for (int i = 0; i < 8; ++i) {
            int f = tid + i * 256;      // 2048 float4 of h tile
            int hrow = f >> 5;
            int kq = f & 31;
            int grow = r0 + hrow;
            float4 g = {0, 0, 0, 0};
            if (grow < N_NODES) g = *(const float4*)(h + (size_t)grow * 512 + kk + kq * 4);
            #pragma unroll
            for (int j = 0; j < 4; ++j) Hs[hrow][kq * 4 + j] = ((const float*)&g)[j];
        }
        #pragma unroll
        for (int i = 0; i < 5; ++i) {
            int f = tid + i * 256;      // 1280 float4 per w matrix
            int k = f / 10;
            int cq = f % 10;
            float4 gl = *(const float4*)(w_l + (size_t)(kk + k) * 40 + cq * 4);
            float4 gr = *(const float4*)(w_r + (size_t)(kk + k) * 40 + cq * 4);
            *(float4*)&Ws[k][cq * 4] = gl;
            *(float4*)&Ws[k][40 + cq * 4] = gr;
        }
        __syncthreads();
        #pragma unroll 4
        for (int k = 0; k < 128; ++k) {
            float hv = Hs[lane][k];
            const float4* wrow = (const float4*)&Ws[k][cg * 20];
            #pragma unroll
            for (int j5 = 0; j5 < 5; ++j5) {
                float4 w4 = wrow[j5];
                acc[j5 * 4 + 0] += hv * w4.x;
                acc[j5 * 4 + 1] += hv * w4.y;
                acc[j5 * 4 + 2] += hv * w4.z;
                acc[j5 * 4 + 3] += hv * w4.w;
            }
        }
        __syncthreads();
    }
    int grow = r0 + lane;
    if (grow < N_NODES) {
        #pragma unroll
        for (int t = 0; t < 20; ++t) {
            int c = cg * 20 + t;
            if (c < 40) p[(size_t)grow * 40 + c] = acc[t];
            else        r[(size_t)grow * 40 + (c - 40)] = acc[t];
        }
    }
}

// out = log_softmax(mean_j p[src] + b2 + r)  one wave per node, lanes 0..39
__global__ void final_kernel(const float* __restrict__ p, const float* __restrict__ rr,
                             const float* __restrict__ b2,
                             const int* __restrict__ row_ptr, const int* __restrict__ csr_src,
                             float* __restrict__ out) {
    int wid = threadIdx.x >> 6;
    int lane = threadIdx.x & 63;
    int n = blockIdx.x * 4 + wid;
    if (n >= N_NODES) return;
    int beg = row_ptr[n], end = row_ptr[n + 1];
    float acc = 0.f;
    if (lane < OUT_DIM) {
        for (int e = beg; e < end; ++e) {
            int s = csr_src[e];
            acc += p[(size_t)s * OUT_DIM + lane];
        }
    }
    int d = end - beg; if (d < 1) d = 1;
    float inv = 1.0f / (float)d;
    float v = (lane < OUT_DIM) ? (acc * inv + b2[lane] + rr[(size_t)n * OUT_DIM + lane])
                               : -INFINITY;
    float m = v;
    #pragma unroll
    for (int off = 32; off; off >>= 1) m = fmaxf(m, __shfl_xor(m, off));
    float ex = (lane < OUT_DIM) ? expf(v - m) : 0.f;
    float ssum = ex;
    #pragma unroll
    for (int off = 32; off; off >>= 1) ssum += __shfl_xor(ssum, off);
    if (lane < OUT_DIM) out[(size_t)n * OUT_DIM + lane] = (v - m) - logf(ssum);
}

extern "C" void kernel_launch(void* const* d_in, const int* in_sizes, int n_in,
                              void* d_out, int out_size, void* d_ws, size_t ws_size,
                              hipStream_t stream) {
    const float* x    = (const float*)d_in[0];
    const int*   edge = (const int*)d_in[1];
    const int*   srce = edge;
    const int*   dste = edge + N_EDGES;
    const float* w1l  = (const float*)d_in[2];
    const float* b1   = (const float*)d_in[3];
    const float* w1r  = (const float*)d_in[4];
    const float* w2l  = (const float*)d_in[5];
    const float* b2   = (const float*)d_in[6];
    const float* w2r  = (const float*)d_in[7];
    float* out = (float*)d_out;

    char* ws = (char*)d_ws;
    size_t off = 0;
    auto alloc = [&](size_t bytes) -> void* {
        void* ptr = ws + off;
        off = (off + bytes + 255) & ~(size_t)255;
        return ptr;
    };
    int* deg     = (int*)alloc((size_t)2 * N_NODES * 4);   // deg + cursor contiguous
    int* cursor  = deg + N_NODES;
    int* row_ptr = (int*)alloc((size_t)(N_NODES + 1) * 4);
    int* csr_src = (int*)alloc((size_t)N_EDGES * 4);
    float* agg1  = (float*)alloc((size_t)N_NODES * IN_DIM * 4);
    float* h     = (float*)alloc((size_t)N_NODES * HID * 4);
    float* p     = (float*)alloc((size_t)N_NODES * OUT_DIM * 4);
    float* rbuf  = (float*)alloc((size_t)N_NODES * OUT_DIM * 4);

    zero_ints<<<(2 * N_NODES + 255) / 256, 256, 0, stream>>>(deg, 2 * N_NODES);
    count_deg<<<(N_EDGES + 255) / 256, 256, 0, stream>>>(dste, deg);
    scan_deg<<<1, 1024, 0, stream>>>(deg, row_ptr);
    fill_csr<<<(N_EDGES + 255) / 256, 256, 0, stream>>>(srce, dste, row_ptr, cursor, csr_src);
    agg_x<<<(N_NODES + 3) / 4, 256, 0, stream>>>(x, row_ptr, csr_src, agg1);
    gemm1<<<dim3((N_NODES + 63) / 64, HID / 64), 256, 0, stream>>>(agg1, x, w1l, w1r, b1, h);
    gemm2<<<(N_NODES + 63) / 64, 256, 0, stream>>>(h, w2l, w2r, p, rbuf);
    final_kernel<<<(N_NODES + 3) / 4, 256, 0, stream>>>(p, rbuf, b2, row_ptr, csr_src, out);
}

// Round 2
// 504.786 us; speedup vs baseline: 1.3638x; 1.3638x over previous
//
#include <hip/hip_runtime.h>
#include <math.h>

#define N_NODES 50000
#define N_EDGES 800000
#define IN_DIM 128
#define HID 512
#define OUT_DIM 40

typedef __attribute__((ext_vector_type(8))) short bf16x8;
typedef __attribute__((ext_vector_type(4))) float f32x4;

__device__ __forceinline__ ushort f2bf(float f) {
    unsigned u = __float_as_uint(f);
    u += 0x7fff + ((u >> 16) & 1);   // round-to-nearest-even
    return (ushort)(u >> 16);
}

__global__ void zero_ints(int* __restrict__ a, int n) {
    int i = blockIdx.x * blockDim.x + threadIdx.x;
    if (i < n) a[i] = 0;
}

__global__ void count_deg(const int* __restrict__ dst, int* __restrict__ deg) {
    int e = blockIdx.x * blockDim.x + threadIdx.x;
    if (e < N_EDGES) atomicAdd(&deg[dst[e]], 1);
}

// single-block exclusive scan over 50000 degrees -> row_ptr[50001]
__global__ void scan_deg(const int* __restrict__ deg, int* __restrict__ row_ptr) {
    __shared__ int sums[1024];
    const int n = N_NODES;
    int tid = threadIdx.x;
    int chunk = (n + 1023) >> 10;
    int start = tid * chunk;
    int end = start + chunk; if (end > n) end = n;
    int s = 0;
    for (int i = start; i < end; ++i) s += deg[i];
    sums[tid] = s;
    __syncthreads();
    for (int off = 1; off < 1024; off <<= 1) {
        int add = (tid >= off) ? sums[tid - off] : 0;
        __syncthreads();
        sums[tid] += add;
        __syncthreads();
    }
    int base = sums[tid] - s;
    for (int i = start; i < end; ++i) { row_ptr[i] = base; base += deg[i]; }
    if (tid == 1023) row_ptr[n] = sums[1023];
}

__global__ void fill_csr(const int* __restrict__ src, const int* __restrict__ dst,
                         const int* __restrict__ row_ptr, int* __restrict__ cursor,
                         int* __restrict__ csr_src) {
    int e = blockIdx.x * blockDim.x + threadIdx.x;
    if (e < N_EDGES) {
        int d = dst[e];
        int pos = atomicAdd(&cursor[d], 1);
        csr_src[row_ptr[d] + pos] = src[e];
    }
}

// one wave per node: mean of x[src] rows -> bf16 into abuf[n][0..127]
__global__ void agg_x(const float* __restrict__ x, const int* __restrict__ row_ptr,
                      const int* __restrict__ csr_src, ushort* __restrict__ abuf) {
    int wid = threadIdx.x >> 6;
    int lane = threadIdx.x & 63;
    int n = blockIdx.x * 4 + wid;
    if (n >= N_NODES) return;
    int beg = row_ptr[n], end = row_ptr[n + 1];
    float ax = 0.f, ay = 0.f;
    for (int e = beg; e < end; ++e) {
        int s = csr_src[e];
        float2 v = *(const float2*)(x + (size_t)s * IN_DIM + lane * 2);
        ax += v.x; ay += v.y;
    }
    int d = end - beg; if (d < 1) d = 1;
    float inv = 1.0f / (float)d;
    ushort2 o; o.x = f2bf(ax * inv); o.y = f2bf(ay * inv);
    *(ushort2*)(abuf + (size_t)n * 256 + lane * 2) = o;
}

// abuf[n][128..255] = bf16(x[n][:])
__global__ void cvt_x(const float* __restrict__ x, ushort* __restrict__ abuf) {
    int i = blockIdx.x * blockDim.x + threadIdx.x;   // over N*32 float4s
    if (i >= N_NODES * 32) return;
    int n = i >> 5, q = i & 31;
    float4 v = *(const float4*)(x + (size_t)n * 128 + q * 4);
    ushort4 o;
    o.x = f2bf(v.x); o.y = f2bf(v.y); o.z = f2bf(v.z); o.w = f2bf(v.w);
    *(ushort4*)(abuf + (size_t)n * 256 + 128 + q * 4) = o;
}

// wt[c][k] = bf16( k<128 ? w1_l[k][c] : w1_r[k-128][c] )   [512][256]
__global__ void cvt_w(const float* __restrict__ wl, const float* __restrict__ wr,
                      ushort* __restrict__ wt) {
    int i = blockIdx.x * blockDim.x + threadIdx.x;   // 512*256
    if (i >= 512 * 256) return;
    int k = i >> 9, c = i & 511;                     // coalesced reads over c
    float v = (k < 128) ? wl[(size_t)k * 512 + c] : wr[(size_t)(k - 128) * 512 + c];
    wt[(size_t)c * 256 + k] = f2bf(v);
}

// h = relu(A @ WT^T + b)  A:[50000][256] bf16, WT:[512][256] bf16 -> h fp32
#define LDP 40   // padded LDS row stride in bf16 elems (80B)
__global__ __launch_bounds__(256) void gemm1_mfma(
    const ushort* __restrict__ A, const ushort* __restrict__ BT,
    const float* __restrict__ bias, float* __restrict__ h) {
    __shared__ ushort As[128 * LDP];
    __shared__ ushort Bs[128 * LDP];
    int tid = threadIdx.x;
    int wave = tid >> 6, lane = tid & 63;
    int wm = wave >> 1, wn = wave & 1;      // 2x2 waves, 64x64 each
    int row0 = blockIdx.x * 128;
    int col0 = blockIdx.y * 128;
    f32x4 acc[4][4] = {};
    for (int kk = 0; kk < 256; kk += 32) {
        #pragma unroll
        for (int i = 0; i < 2; ++i) {
            int c = tid + i * 256;          // 512 chunks of 8 bf16
            int r = c >> 2, ks = c & 3;
            int gr = row0 + r;
            int4 va = {0, 0, 0, 0};
            if (gr < N_NODES) va = *(const int4*)(A + (size_t)gr * 256 + kk + ks * 8);
            *(int4*)(As + r * LDP + ks * 8) = va;
            int gc = col0 + r;
            int4 vb = *(const int4*)(BT + (size_t)gc * 256 + kk + ks * 8);
            *(int4*)(Bs + r * LDP + ks * 8) = vb;
        }
        __syncthreads();
        int ksl = (lane >> 4) * 8;
        bf16x8 af[4], bfr[4];
        #pragma unroll
        for (int m = 0; m < 4; ++m)
            af[m] = *(const bf16x8*)(As + (wm * 64 + m * 16 + (lane & 15)) * LDP + ksl);
        #pragma unroll
        for (int n = 0; n < 4; ++n)
            bfr[n] = *(const bf16x8*)(Bs + (wn * 64 + n * 16 + (lane & 15)) * LDP + ksl);
        #pragma unroll
        for (int m = 0; m < 4; ++m)
            #pragma unroll
            for (int n = 0; n < 4; ++n)
                acc[m][n] = __builtin_amdgcn_mfma_f32_16x16x32_bf16(af[m], bfr[n], acc[m][n], 0, 0, 0);
        __syncthreads();
    }
    #pragma unroll
    for (int m = 0; m < 4; ++m) {
        #pragma unroll
        for (int j = 0; j < 4; ++j) {
            int grow = row0 + wm * 64 + m * 16 + (lane >> 4) * 4 + j;
            if (grow >= N_NODES) continue;
            #pragma unroll
            for (int n = 0; n < 4; ++n) {
                int gcol = col0 + wn * 64 + n * 16 + (lane & 15);
                float v = acc[m][n][j] + bias[gcol];
                h[(size_t)grow * 512 + gcol] = v > 0.f ? v : 0.f;
            }
        }
    }
}

// p = h @ w2_l ; r = h @ w2_r    [50000,512]x[512,40] both in one pass over h
__global__ __launch_bounds__(256) void gemm2(
    const float* __restrict__ h, const float* __restrict__ w_l,
    const float* __restrict__ w_r, float* __restrict__ p, float* __restrict__ r) {
    __shared__ float Hs[64][133];
    __shared__ float Ws[128][80];
    int tid = threadIdx.x;
    int r0 = blockIdx.x * 64;
    int lane = tid & 63;
    int cg = tid >> 6;
    float acc[20] = {};
    for (int kk = 0; kk < 512; kk += 128) {
        #pragma unroll
        for (int i = 0; i < 8; ++i) {
            int f = tid + i * 256;
            int hrow = f >> 5;
            int kq = f & 31;
            int grow = r0 + hrow;
            float4 g = {0, 0, 0, 0};
            if (grow < N_NODES) g = *(const float4*)(h + (size_t)grow * 512 + kk + kq * 4);
            #pragma unroll
            for (int j = 0; j < 4; ++j) Hs[hrow][kq * 4 + j] = ((const float*)&g)[j];
        }
        #pragma unroll
        for (int i = 0; i < 5; ++i) {
            int f = tid + i * 256;
            int k = f / 10;
            int cq = f % 10;
            float4 gl = *(const float4*)(w_l + (size_t)(kk + k) * 40 + cq * 4);
            float4 gr = *(const float4*)(w_r + (size_t)(kk + k) * 40 + cq * 4);
            *(float4*)&Ws[k][cq * 4] = gl;
            *(float4*)&Ws[k][40 + cq * 4] = gr;
        }
        __syncthreads();
        #pragma unroll 4
        for (int k = 0; k < 128; ++k) {
            float hv = Hs[lane][k];
            const float4* wrow = (const float4*)&Ws[k][cg * 20];
            #pragma unroll
            for (int j5 = 0; j5 < 5; ++j5) {
                float4 w4 = wrow[j5];
                acc[j5 * 4 + 0] += hv * w4.x;
                acc[j5 * 4 + 1] += hv * w4.y;
                acc[j5 * 4 + 2] += hv * w4.z;
                acc[j5 * 4 + 3] += hv * w4.w;
            }
        }
        __syncthreads();
    }
    int grow = r0 + lane;
    if (grow < N_NODES) {
        #pragma unroll
        for (int t = 0; t < 20; ++t) {
            int c = cg * 20 + t;
            if (c < 40) p[(size_t)grow * 40 + c] = acc[t];
            else        r[(size_t)grow * 40 + (c - 40)] = acc[t];
        }
    }
}

// out = log_softmax(mean_j p[src] + b2 + r)  one wave per node, lanes 0..39
__global__ void final_kernel(const float* __restrict__ p, const float* __restrict__ rr,
                             const float* __restrict__ b2,
                             const int* __restrict__ row_ptr, const int* __restrict__ csr_src,
                             float* __restrict__ out) {
    int wid = threadIdx.x >> 6;
    int lane = threadIdx.x & 63;
    int n = blockIdx.x * 4 + wid;
    if (n >= N_NODES) return;
    int beg = row_ptr[n], end = row_ptr[n + 1];
    float acc = 0.f;
    if (lane < OUT_DIM) {
        for (int e = beg; e < end; ++e) {
            int s = csr_src[e];
            acc += p[(size_t)s * OUT_DIM + lane];
        }
    }
    int d = end - beg; if (d < 1) d = 1;
    float inv = 1.0f / (float)d;
    float v = (lane < OUT_DIM) ? (acc * inv + b2[lane] + rr[(size_t)n * OUT_DIM + lane])
                               : -INFINITY;
    float m = v;
    #pragma unroll
    for (int off = 32; off; off >>= 1) m = fmaxf(m, __shfl_xor(m, off));
    float ex = (lane < OUT_DIM) ? expf(v - m) : 0.f;
    float ssum = ex;
    #pragma unroll
    for (int off = 32; off; off >>= 1) ssum += __shfl_xor(ssum, off);
    if (lane < OUT_DIM) out[(size_t)n * OUT_DIM + lane] = (v - m) - logf(ssum);
}

extern "C" void kernel_launch(void* const* d_in, const int* in_sizes, int n_in,
                              void* d_out, int out_size, void* d_ws, size_t ws_size,
                              hipStream_t stream) {
    const float* x    = (const float*)d_in[0];
    const int*   edge = (const int*)d_in[1];
    const int*   srce = edge;
    const int*   dste = edge + N_EDGES;
    const float* w1l  = (const float*)d_in[2];
    const float* b1   = (const float*)d_in[3];
    const float* w1r  = (const float*)d_in[4];
    const float* w2l  = (const float*)d_in[5];
    const float* b2   = (const float*)d_in[6];
    const float* w2r  = (const float*)d_in[7];
    float* out = (float*)d_out;

    char* ws = (char*)d_ws;
    size_t off = 0;
    auto alloc = [&](size_t bytes) -> void* {
        void* ptr = ws + off;
        off = (off + bytes + 255) & ~(size_t)255;
        return ptr;
    };
    int* deg     = (int*)alloc((size_t)2 * N_NODES * 4);
    int* cursor  = deg + N_NODES;
    int* row_ptr = (int*)alloc((size_t)(N_NODES + 1) * 4);
    int* csr_src = (int*)alloc((size_t)N_EDGES * 4);
    ushort* abuf = (ushort*)alloc((size_t)N_NODES * 256 * 2);   // [agg|x] bf16
    ushort* wt   = (ushort*)alloc((size_t)512 * 256 * 2);       // [w1_l;w1_r]^T bf16
    float* h     = (float*)alloc((size_t)N_NODES * HID * 4);
    float* p     = (float*)alloc((size_t)N_NODES * OUT_DIM * 4);
    float* rbuf  = (float*)alloc((size_t)N_NODES * OUT_DIM * 4);

    zero_ints<<<(2 * N_NODES + 255) / 256, 256, 0, stream>>>(deg, 2 * N_NODES);
    count_deg<<<(N_EDGES + 255) / 256, 256, 0, stream>>>(dste, deg);
    scan_deg<<<1, 1024, 0, stream>>>(deg, row_ptr);
    fill_csr<<<(N_EDGES + 255) / 256, 256, 0, stream>>>(srce, dste, row_ptr, cursor, csr_src);
    cvt_x<<<(N_NODES * 32 + 255) / 256, 256, 0, stream>>>(x, abuf);
    cvt_w<<<(512 * 256 + 255) / 256, 256, 0, stream>>>(w1l, w1r, wt);
    agg_x<<<(N_NODES + 3) / 4, 256, 0, stream>>>(x, row_ptr, csr_src, abuf);
    gemm1_mfma<<<dim3((N_NODES + 127) / 128, 4), 256, 0, stream>>>(abuf, wt, b1, h);
    gemm2<<<(N_NODES + 63) / 64, 256, 0, stream>>>(h, w2l, w2r, p, rbuf);
    final_kernel<<<(N_NODES + 3) / 4, 256, 0, stream>>>(p, rbuf, b2, row_ptr, csr_src, out);
}

// Round 3
// 339.859 us; speedup vs baseline: 2.0256x; 1.4853x over previous
//
#include <hip/hip_runtime.h>
#include <math.h>

#define N_NODES 50000
#define N_EDGES 800000
#define IN_DIM 128
#define HID 512
#define OUT_DIM 40

typedef __attribute__((ext_vector_type(8))) short bf16x8;
typedef __attribute__((ext_vector_type(4))) float f32x4;

__device__ __forceinline__ ushort f2bf(float f) {
    unsigned u = __float_as_uint(f);
    u += 0x7fff + ((u >> 16) & 1);   // round-to-nearest-even
    return (ushort)(u >> 16);
}

__global__ void zero_ints(int* __restrict__ a, int n) {
    int i = blockIdx.x * blockDim.x + threadIdx.x;
    if (i < n) a[i] = 0;
}

__global__ void count_deg(const int* __restrict__ dst, int* __restrict__ deg) {
    int e = blockIdx.x * blockDim.x + threadIdx.x;
    if (e < N_EDGES) atomicAdd(&deg[dst[e]], 1);
}

// single-block exclusive scan over 50000 degrees -> row_ptr[50001]
__global__ void scan_deg(const int* __restrict__ deg, int* __restrict__ row_ptr) {
    __shared__ int sums[1024];
    const int n = N_NODES;
    int tid = threadIdx.x;
    int chunk = (n + 1023) >> 10;
    int start = tid * chunk;
    int end = start + chunk; if (end > n) end = n;
    int s = 0;
    for (int i = start; i < end; ++i) s += deg[i];
    sums[tid] = s;
    __syncthreads();
    for (int off = 1; off < 1024; off <<= 1) {
        int add = (tid >= off) ? sums[tid - off] : 0;
        __syncthreads();
        sums[tid] += add;
        __syncthreads();
    }
    int base = sums[tid] - s;
    for (int i = start; i < end; ++i) { row_ptr[i] = base; base += deg[i]; }
    if (tid == 1023) row_ptr[n] = sums[1023];
}

__global__ void fill_csr(const int* __restrict__ src, const int* __restrict__ dst,
                         const int* __restrict__ row_ptr, int* __restrict__ cursor,
                         int* __restrict__ csr_src) {
    int e = blockIdx.x * blockDim.x + threadIdx.x;
    if (e < N_EDGES) {
        int d = dst[e];
        int pos = atomicAdd(&cursor[d], 1);
        csr_src[row_ptr[d] + pos] = src[e];
    }
}

// one wave per node: mean of x[src] rows -> bf16 into abuf[n][0..127]
// half-wave per edge: 32 lanes x float4 = one 512B row; 2-deep unroll for MLP
__global__ void agg_x(const float* __restrict__ x, const int* __restrict__ row_ptr,
                      const int* __restrict__ csr_src, ushort* __restrict__ abuf) {
    int wid = threadIdx.x >> 6;
    int lane = threadIdx.x & 63;
    int n = blockIdx.x * 4 + wid;
    if (n >= N_NODES) return;
    int beg = row_ptr[n], end = row_ptr[n + 1];
    int half = lane >> 5, l32 = lane & 31;
    float4 a0 = {0, 0, 0, 0}, a1 = {0, 0, 0, 0};
    int e = beg + half;
    for (; e + 2 < end; e += 4) {
        int s0 = csr_src[e], s1 = csr_src[e + 2];
        float4 v0 = *(const float4*)(x + (size_t)s0 * IN_DIM + l32 * 4);
        float4 v1 = *(const float4*)(x + (size_t)s1 * IN_DIM + l32 * 4);
        a0.x += v0.x; a0.y += v0.y; a0.z += v0.z; a0.w += v0.w;
        a1.x += v1.x; a1.y += v1.y; a1.z += v1.z; a1.w += v1.w;
    }
    if (e < end) {
        int s = csr_src[e];
        float4 v = *(const float4*)(x + (size_t)s * IN_DIM + l32 * 4);
        a0.x += v.x; a0.y += v.y; a0.z += v.z; a0.w += v.w;
    }
    a0.x += a1.x; a0.y += a1.y; a0.z += a1.z; a0.w += a1.w;
    a0.x += __shfl_xor(a0.x, 32);
    a0.y += __shfl_xor(a0.y, 32);
    a0.z += __shfl_xor(a0.z, 32);
    a0.w += __shfl_xor(a0.w, 32);
    int d = end - beg; if (d < 1) d = 1;
    float inv = 1.0f / (float)d;
    if (half == 0) {
        ushort4 o;
        o.x = f2bf(a0.x * inv); o.y = f2bf(a0.y * inv);
        o.z = f2bf(a0.z * inv); o.w = f2bf(a0.w * inv);
        *(ushort4*)(abuf + (size_t)n * 256 + l32 * 4) = o;
    }
}

// abuf[n][128..255] = bf16(x[n][:])
__global__ void cvt_x(const float* __restrict__ x, ushort* __restrict__ abuf) {
    int i = blockIdx.x * blockDim.x + threadIdx.x;
    if (i >= N_NODES * 32) return;
    int n = i >> 5, q = i & 31;
    float4 v = *(const float4*)(x + (size_t)n * 128 + q * 4);
    ushort4 o;
    o.x = f2bf(v.x); o.y = f2bf(v.y); o.z = f2bf(v.z); o.w = f2bf(v.w);
    *(ushort4*)(abuf + (size_t)n * 256 + 128 + q * 4) = o;
}

// wt[c][k] = bf16( k<128 ? w1_l[k][c] : w1_r[k-128][c] )   [512][256]
__global__ void cvt_w(const float* __restrict__ wl, const float* __restrict__ wr,
                      ushort* __restrict__ wt) {
    int i = blockIdx.x * blockDim.x + threadIdx.x;
    if (i >= 512 * 256) return;
    int k = i >> 9, c = i & 511;
    float v = (k < 128) ? wl[(size_t)k * 512 + c] : wr[(size_t)(k - 128) * 512 + c];
    wt[(size_t)c * 256 + k] = f2bf(v);
}

// wt2[c][k] = bf16( c<40 ? w2_l[k][c] : w2_r[k][c-40] )   [80][512]
__global__ void cvt_w2(const float* __restrict__ wl, const float* __restrict__ wr,
                       ushort* __restrict__ wt2) {
    int i = blockIdx.x * blockDim.x + threadIdx.x;
    if (i >= 80 * 512) return;
    int c = i >> 9, k = i & 511;
    float v = (c < 40) ? wl[(size_t)k * 40 + c] : wr[(size_t)k * 40 + (c - 40)];
    wt2[(size_t)c * 512 + k] = f2bf(v);
}

// h = relu(A @ WT^T + b)  A:[50000][256] bf16, WT:[512][256] bf16 -> h bf16
#define LDP 40   // padded LDS row stride (bf16 elems), 80B
__global__ __launch_bounds__(256) void gemm1_mfma(
    const ushort* __restrict__ A, const ushort* __restrict__ BT,
    const float* __restrict__ bias, ushort* __restrict__ h) {
    __shared__ ushort As[128 * LDP];
    __shared__ ushort Bs[128 * LDP];
    int tid = threadIdx.x;
    int wave = tid >> 6, lane = tid & 63;
    int wm = wave >> 1, wn = wave & 1;      // 2x2 waves, 64x64 each
    int row0 = blockIdx.x * 128;
    int col0 = blockIdx.y * 128;
    f32x4 acc[4][4] = {};
    for (int kk = 0; kk < 256; kk += 32) {
        #pragma unroll
        for (int i = 0; i < 2; ++i) {
            int c = tid + i * 256;
            int r = c >> 2, ks = c & 3;
            int gr = row0 + r;
            int4 va = {0, 0, 0, 0};
            if (gr < N_NODES) va = *(const int4*)(A + (size_t)gr * 256 + kk + ks * 8);
            *(int4*)(As + r * LDP + ks * 8) = va;
            int gc = col0 + r;
            int4 vb = *(const int4*)(BT + (size_t)gc * 256 + kk + ks * 8);
            *(int4*)(Bs + r * LDP + ks * 8) = vb;
        }
        __syncthreads();
        int ksl = (lane >> 4) * 8;
        bf16x8 af[4], bfr[4];
        #pragma unroll
        for (int m = 0; m < 4; ++m)
            af[m] = *(const bf16x8*)(As + (wm * 64 + m * 16 + (lane & 15)) * LDP + ksl);
        #pragma unroll
        for (int n = 0; n < 4; ++n)
            bfr[n] = *(const bf16x8*)(Bs + (wn * 64 + n * 16 + (lane & 15)) * LDP + ksl);
        #pragma unroll
        for (int m = 0; m < 4; ++m)
            #pragma unroll
            for (int n = 0; n < 4; ++n)
                acc[m][n] = __builtin_amdgcn_mfma_f32_16x16x32_bf16(af[m], bfr[n], acc[m][n], 0, 0, 0);
        __syncthreads();
    }
    #pragma unroll
    for (int m = 0; m < 4; ++m) {
        #pragma unroll
        for (int j = 0; j < 4; ++j) {
            int grow = row0 + wm * 64 + m * 16 + (lane >> 4) * 4 + j;
            if (grow >= N_NODES) continue;
            #pragma unroll
            for (int n = 0; n < 4; ++n) {
                int gcol = col0 + wn * 64 + n * 16 + (lane & 15);
                float v = acc[m][n][j] + bias[gcol];
                h[(size_t)grow * 512 + gcol] = f2bf(v > 0.f ? v : 0.f);
            }
        }
    }
}

// [p|r] = h @ wt2^T   h:[50000][512] bf16, wt2:[80][512] bf16
#define LDB2 72
__global__ __launch_bounds__(256) void gemm2_mfma(
    const ushort* __restrict__ hbf, const ushort* __restrict__ wt2,
    float* __restrict__ p, float* __restrict__ r) {
    __shared__ ushort As[128 * LDB2];
    __shared__ ushort Bs[80 * LDB2];
    int tid = threadIdx.x;
    int wave = tid >> 6, lane = tid & 63;
    int row0 = blockIdx.x * 128;
    f32x4 acc[2][5] = {};
    for (int kk = 0; kk < 512; kk += 64) {
        #pragma unroll
        for (int i = 0; i < 4; ++i) {
            int c = tid + i * 256;          // 1024 chunks of 8 bf16
            int rr_ = c >> 3, ks = c & 7;
            int gr = row0 + rr_;
            int4 va = {0, 0, 0, 0};
            if (gr < N_NODES) va = *(const int4*)(hbf + (size_t)gr * 512 + kk + ks * 8);
            *(int4*)(As + rr_ * LDB2 + ks * 8) = va;
        }
        #pragma unroll
        for (int i = 0; i < 3; ++i) {
            int c = tid + i * 256;          // 640 chunks
            if (c < 640) {
                int rr_ = c >> 3, ks = c & 7;
                int4 vb = *(const int4*)(wt2 + (size_t)rr_ * 512 + kk + ks * 8);
                *(int4*)(Bs + rr_ * LDB2 + ks * 8) = vb;
            }
        }
        __syncthreads();
        #pragma unroll
        for (int kb = 0; kb < 64; kb += 32) {
            int ko = kb + (lane >> 4) * 8;
            bf16x8 af[2], bfr[5];
            #pragma unroll
            for (int m = 0; m < 2; ++m)
                af[m] = *(const bf16x8*)(As + (wave * 32 + m * 16 + (lane & 15)) * LDB2 + ko);
            #pragma unroll
            for (int n = 0; n < 5; ++n)
                bfr[n] = *(const bf16x8*)(Bs + (n * 16 + (lane & 15)) * LDB2 + ko);
            #pragma unroll
            for (int m = 0; m < 2; ++m)
                #pragma unroll
                for (int n = 0; n < 5; ++n)
                    acc[m][n] = __builtin_amdgcn_mfma_f32_16x16x32_bf16(af[m], bfr[n], acc[m][n], 0, 0, 0);
        }
        __syncthreads();
    }
    #pragma unroll
    for (int m = 0; m < 2; ++m) {
        #pragma unroll
        for (int j = 0; j < 4; ++j) {
            int grow = row0 + wave * 32 + m * 16 + (lane >> 4) * 4 + j;
            if (grow >= N_NODES) continue;
            #pragma unroll
            for (int n = 0; n < 5; ++n) {
                int col = n * 16 + (lane & 15);
                float v = acc[m][n][j];
                if (col < 40) p[(size_t)grow * 40 + col] = v;
                else          r[(size_t)grow * 40 + (col - 40)] = v;
            }
        }
    }
}

// out = log_softmax(mean_j p[src] + b2 + r)  one wave per node, lanes 0..39
__global__ void final_kernel(const float* __restrict__ p, const float* __restrict__ rr,
                             const float* __restrict__ b2,
                             const int* __restrict__ row_ptr, const int* __restrict__ csr_src,
                             float* __restrict__ out) {
    int wid = threadIdx.x >> 6;
    int lane = threadIdx.x & 63;
    int n = blockIdx.x * 4 + wid;
    if (n >= N_NODES) return;
    int beg = row_ptr[n], end = row_ptr[n + 1];
    float acc0 = 0.f, acc1 = 0.f;
    int e = beg;
    if (lane < OUT_DIM) {
        for (; e + 1 < end; e += 2) {
            int s0 = csr_src[e], s1 = csr_src[e + 1];
            acc0 += p[(size_t)s0 * OUT_DIM + lane];
            acc1 += p[(size_t)s1 * OUT_DIM + lane];
        }
        if (e < end) acc0 += p[(size_t)csr_src[e] * OUT_DIM + lane];
    }
    int d = end - beg; if (d < 1) d = 1;
    float inv = 1.0f / (float)d;
    float v = (lane < OUT_DIM)
                  ? ((acc0 + acc1) * inv + b2[lane] + rr[(size_t)n * OUT_DIM + lane])
                  : -INFINITY;
    float m = v;
    #pragma unroll
    for (int off = 32; off; off >>= 1) m = fmaxf(m, __shfl_xor(m, off));
    float ex = (lane < OUT_DIM) ? expf(v - m) : 0.f;
    float ssum = ex;
    #pragma unroll
    for (int off = 32; off; off >>= 1) ssum += __shfl_xor(ssum, off);
    if (lane < OUT_DIM) out[(size_t)n * OUT_DIM + lane] = (v - m) - logf(ssum);
}

extern "C" void kernel_launch(void* const* d_in, const int* in_sizes, int n_in,
                              void* d_out, int out_size, void* d_ws, size_t ws_size,
                              hipStream_t stream) {
    const float* x    = (const float*)d_in[0];
    const int*   edge = (const int*)d_in[1];
    const int*   srce = edge;
    const int*   dste = edge + N_EDGES;
    const float* w1l  = (const float*)d_in[2];
    const float* b1   = (const float*)d_in[3];
    const float* w1r  = (const float*)d_in[4];
    const float* w2l  = (const float*)d_in[5];
    const float* b2   = (const float*)d_in[6];
    const float* w2r  = (const float*)d_in[7];
    float* out = (float*)d_out;

    char* ws = (char*)d_ws;
    size_t off = 0;
    auto alloc = [&](size_t bytes) -> void* {
        void* ptr = ws + off;
        off = (off + bytes + 255) & ~(size_t)255;
        return ptr;
    };
    int* deg     = (int*)alloc((size_t)2 * N_NODES * 4);
    int* cursor  = deg + N_NODES;
    int* row_ptr = (int*)alloc((size_t)(N_NODES + 1) * 4);
    int* csr_src = (int*)alloc((size_t)N_EDGES * 4);
    ushort* abuf = (ushort*)alloc((size_t)N_NODES * 256 * 2);   // [agg|x] bf16
    ushort* wt   = (ushort*)alloc((size_t)512 * 256 * 2);       // [w1_l;w1_r]^T bf16
    ushort* wt2  = (ushort*)alloc((size_t)80 * 512 * 2);        // [w2_l|w2_r]^T bf16
    ushort* h    = (ushort*)alloc((size_t)N_NODES * HID * 2);   // h bf16
    float* p     = (float*)alloc((size_t)N_NODES * OUT_DIM * 4);
    float* rbuf  = (float*)alloc((size_t)N_NODES * OUT_DIM * 4);

    zero_ints<<<(2 * N_NODES + 255) / 256, 256, 0, stream>>>(deg, 2 * N_NODES);
    count_deg<<<(N_EDGES + 255) / 256, 256, 0, stream>>>(dste, deg);
    scan_deg<<<1, 1024, 0, stream>>>(deg, row_ptr);
    fill_csr<<<(N_EDGES + 255) / 256, 256, 0, stream>>>(srce, dste, row_ptr, cursor, csr_src);
    cvt_x<<<(N_NODES * 32 + 255) / 256, 256, 0, stream>>>(x, abuf);
    cvt_w<<<(512 * 256 + 255) / 256, 256, 0, stream>>>(w1l, w1r, wt);
    cvt_w2<<<(80 * 512 + 255) / 256, 256, 0, stream>>>(w2l, w2r, wt2);
    agg_x<<<(N_NODES + 3) / 4, 256, 0, stream>>>(x, row_ptr, csr_src, abuf);
    gemm1_mfma<<<dim3((N_NODES + 127) / 128, 4), 256, 0, stream>>>(abuf, wt, b1, h);
    gemm2_mfma<<<(N_NODES + 127) / 128, 256, 0, stream>>>(h, wt2, p, rbuf);
    final_kernel<<<(N_NODES + 3) / 4, 256, 0, stream>>>(p, rbuf, b2, row_ptr, csr_src, out);
}

// Round 4
// 279.784 us; speedup vs baseline: 2.4605x; 1.2147x over previous
//
#include <hip/hip_runtime.h>
#include <math.h>

#define N_NODES 50000
#define N_EDGES 800000
#define IN_DIM 128
#define HID 512
#define OUT_DIM 40
#define NB_SCAN ((N_NODES + 255) / 256)   // 196

typedef __attribute__((ext_vector_type(8))) short bf16x8;
typedef __attribute__((ext_vector_type(4))) float f32x4;

__device__ __forceinline__ ushort f2bf(float f) {
    unsigned u = __float_as_uint(f);
    u += 0x7fff + ((u >> 16) & 1);   // round-to-nearest-even
    return (ushort)(u >> 16);
}

__global__ void zero_ints(int* __restrict__ a, int n) {
    int i = blockIdx.x * blockDim.x + threadIdx.x;
    if (i < n) a[i] = 0;
}

__global__ void count_deg(const int* __restrict__ dst, int* __restrict__ deg) {
    int e = blockIdx.x * blockDim.x + threadIdx.x;
    if (e < N_EDGES) atomicAdd(&deg[dst[e]], 1);
}

// --- 3-stage parallel exclusive scan: deg[50000] -> row_ptr[50001] ---
__global__ void deg_block_sums(const int* __restrict__ deg, int* __restrict__ bsum) {
    __shared__ int red[256];
    int tid = threadIdx.x;
    int i = blockIdx.x * 256 + tid;
    red[tid] = (i < N_NODES) ? deg[i] : 0;
    __syncthreads();
    #pragma unroll
    for (int off = 128; off; off >>= 1) {
        if (tid < off) red[tid] += red[tid + off];
        __syncthreads();
    }
    if (tid == 0) bsum[blockIdx.x] = red[0];
}

__global__ void scan_bsum(int* __restrict__ bsum) {
    __shared__ int s[256];
    int tid = threadIdx.x;
    int v = (tid < NB_SCAN) ? bsum[tid] : 0;
    s[tid] = v;
    __syncthreads();
    #pragma unroll
    for (int off = 1; off < 256; off <<= 1) {
        int add = (tid >= off) ? s[tid - off] : 0;
        __syncthreads();
        s[tid] += add;
        __syncthreads();
    }
    if (tid < NB_SCAN) bsum[tid] = s[tid] - v;   // exclusive
}

__global__ void scan_fill(const int* __restrict__ deg, const int* __restrict__ bsum,
                          int* __restrict__ row_ptr) {
    __shared__ int s[256];
    int tid = threadIdx.x;
    int i = blockIdx.x * 256 + tid;
    int v = (i < N_NODES) ? deg[i] : 0;
    s[tid] = v;
    __syncthreads();
    #pragma unroll
    for (int off = 1; off < 256; off <<= 1) {
        int add = (tid >= off) ? s[tid - off] : 0;
        __syncthreads();
        s[tid] += add;
        __syncthreads();
    }
    int excl = s[tid] - v + bsum[blockIdx.x];
    if (i < N_NODES) row_ptr[i] = excl;
    if (i == N_NODES - 1) row_ptr[N_NODES] = excl + v;
}

__global__ void fill_csr(const int* __restrict__ src, const int* __restrict__ dst,
                         const int* __restrict__ row_ptr, int* __restrict__ cursor,
                         int* __restrict__ csr_src) {
    int e = blockIdx.x * blockDim.x + threadIdx.x;
    if (e < N_EDGES) {
        int d = dst[e];
        int pos = atomicAdd(&cursor[d], 1);
        csr_src[row_ptr[d] + pos] = src[e];
    }
}

// one wave per node: mean of x[src] rows -> bf16 into abuf[n][0..127]
// half-wave per edge (32 lanes x float4 = 512B row), 4 rows in flight per half
__global__ void agg_x(const float* __restrict__ x, const int* __restrict__ row_ptr,
                      const int* __restrict__ csr_src, ushort* __restrict__ abuf) {
    int wid = threadIdx.x >> 6;
    int lane = threadIdx.x & 63;
    int n = blockIdx.x * 4 + wid;
    if (n >= N_NODES) return;
    int beg = row_ptr[n], end = row_ptr[n + 1];
    int half = lane >> 5, l32 = lane & 31;
    float4 a0 = {0, 0, 0, 0}, a1 = {0, 0, 0, 0}, a2 = {0, 0, 0, 0}, a3 = {0, 0, 0, 0};
    int e = beg + half;
    for (; e + 6 < end; e += 8) {
        int s0 = csr_src[e], s1 = csr_src[e + 2], s2 = csr_src[e + 4], s3 = csr_src[e + 6];
        float4 v0 = *(const float4*)(x + (size_t)s0 * IN_DIM + l32 * 4);
        float4 v1 = *(const float4*)(x + (size_t)s1 * IN_DIM + l32 * 4);
        float4 v2 = *(const float4*)(x + (size_t)s2 * IN_DIM + l32 * 4);
        float4 v3 = *(const float4*)(x + (size_t)s3 * IN_DIM + l32 * 4);
        a0.x += v0.x; a0.y += v0.y; a0.z += v0.z; a0.w += v0.w;
        a1.x += v1.x; a1.y += v1.y; a1.z += v1.z; a1.w += v1.w;
        a2.x += v2.x; a2.y += v2.y; a2.z += v2.z; a2.w += v2.w;
        a3.x += v3.x; a3.y += v3.y; a3.z += v3.z; a3.w += v3.w;
    }
    for (; e < end; e += 2) {
        int s = csr_src[e];
        float4 v = *(const float4*)(x + (size_t)s * IN_DIM + l32 * 4);
        a0.x += v.x; a0.y += v.y; a0.z += v.z; a0.w += v.w;
    }
    a0.x += a1.x + a2.x + a3.x;
    a0.y += a1.y + a2.y + a3.y;
    a0.z += a1.z + a2.z + a3.z;
    a0.w += a1.w + a2.w + a3.w;
    a0.x += __shfl_xor(a0.x, 32);
    a0.y += __shfl_xor(a0.y, 32);
    a0.z += __shfl_xor(a0.z, 32);
    a0.w += __shfl_xor(a0.w, 32);
    int d = end - beg; if (d < 1) d = 1;
    float inv = 1.0f / (float)d;
    if (half == 0) {
        ushort4 o;
        o.x = f2bf(a0.x * inv); o.y = f2bf(a0.y * inv);
        o.z = f2bf(a0.z * inv); o.w = f2bf(a0.w * inv);
        *(ushort4*)(abuf + (size_t)n * 256 + l32 * 4) = o;
    }
}

// abuf[n][128..255] = bf16(x[n][:])
__global__ void cvt_x(const float* __restrict__ x, ushort* __restrict__ abuf) {
    int i = blockIdx.x * blockDim.x + threadIdx.x;
    if (i >= N_NODES * 32) return;
    int n = i >> 5, q = i & 31;
    float4 v = *(const float4*)(x + (size_t)n * 128 + q * 4);
    ushort4 o;
    o.x = f2bf(v.x); o.y = f2bf(v.y); o.z = f2bf(v.z); o.w = f2bf(v.w);
    *(ushort4*)(abuf + (size_t)n * 256 + 128 + q * 4) = o;
}

// wt[c][k] = bf16( k<128 ? w1_l[k][c] : w1_r[k-128][c] )   [512][256]
__global__ void cvt_w(const float* __restrict__ wl, const float* __restrict__ wr,
                      ushort* __restrict__ wt) {
    int i = blockIdx.x * blockDim.x + threadIdx.x;
    if (i >= 512 * 256) return;
    int k = i >> 9, c = i & 511;
    float v = (k < 128) ? wl[(size_t)k * 512 + c] : wr[(size_t)(k - 128) * 512 + c];
    wt[(size_t)c * 256 + k] = f2bf(v);
}

// wt2[c][k] = bf16( c<40 ? w2_l[k][c] : w2_r[k][c-40] )   [80][512]
__global__ void cvt_w2(const float* __restrict__ wl, const float* __restrict__ wr,
                       ushort* __restrict__ wt2) {
    int i = blockIdx.x * blockDim.x + threadIdx.x;
    if (i >= 80 * 512) return;
    int c = i >> 9, k = i & 511;
    float v = (c < 40) ? wl[(size_t)k * 40 + c] : wr[(size_t)k * 40 + (c - 40)];
    wt2[(size_t)c * 512 + k] = f2bf(v);
}

// h = relu(A @ WT^T + b)  A:[50000][256] bf16, WT:[512][256] bf16 -> h bf16
#define LDP 40   // padded LDS row stride (bf16 elems), 80B
__global__ __launch_bounds__(256) void gemm1_mfma(
    const ushort* __restrict__ A, const ushort* __restrict__ BT,
    const float* __restrict__ bias, ushort* __restrict__ h) {
    __shared__ ushort As[128 * LDP];
    __shared__ ushort Bs[128 * LDP];
    int tid = threadIdx.x;
    int wave = tid >> 6, lane = tid & 63;
    int wm = wave >> 1, wn = wave & 1;      // 2x2 waves, 64x64 each
    int row0 = blockIdx.x * 128;
    int col0 = blockIdx.y * 128;
    f32x4 acc[4][4] = {};
    for (int kk = 0; kk < 256; kk += 32) {
        #pragma unroll
        for (int i = 0; i < 2; ++i) {
            int c = tid + i * 256;
            int r = c >> 2, ks = c & 3;
            int gr = row0 + r;
            int4 va = {0, 0, 0, 0};
            if (gr < N_NODES) va = *(const int4*)(A + (size_t)gr * 256 + kk + ks * 8);
            *(int4*)(As + r * LDP + ks * 8) = va;
            int gc = col0 + r;
            int4 vb = *(const int4*)(BT + (size_t)gc * 256 + kk + ks * 8);
            *(int4*)(Bs + r * LDP + ks * 8) = vb;
        }
        __syncthreads();
        int ksl = (lane >> 4) * 8;
        bf16x8 af[4], bfr[4];
        #pragma unroll
        for (int m = 0; m < 4; ++m)
            af[m] = *(const bf16x8*)(As + (wm * 64 + m * 16 + (lane & 15)) * LDP + ksl);
        #pragma unroll
        for (int n = 0; n < 4; ++n)
            bfr[n] = *(const bf16x8*)(Bs + (wn * 64 + n * 16 + (lane & 15)) * LDP + ksl);
        #pragma unroll
        for (int m = 0; m < 4; ++m)
            #pragma unroll
            for (int n = 0; n < 4; ++n)
                acc[m][n] = __builtin_amdgcn_mfma_f32_16x16x32_bf16(af[m], bfr[n], acc[m][n], 0, 0, 0);
        __syncthreads();
    }
    #pragma unroll
    for (int m = 0; m < 4; ++m) {
        #pragma unroll
        for (int j = 0; j < 4; ++j) {
            int grow = row0 + wm * 64 + m * 16 + (lane >> 4) * 4 + j;
            if (grow >= N_NODES) continue;
            #pragma unroll
            for (int n = 0; n < 4; ++n) {
                int gcol = col0 + wn * 64 + n * 16 + (lane & 15);
                float v = acc[m][n][j] + bias[gcol];
                h[(size_t)grow * 512 + gcol] = f2bf(v > 0.f ? v : 0.f);
            }
        }
    }
}

// [p|r] = h @ wt2^T   h:[50000][512] bf16, wt2:[80][512] bf16
#define LDB2 72
__global__ __launch_bounds__(256) void gemm2_mfma(
    const ushort* __restrict__ hbf, const ushort* __restrict__ wt2,
    float* __restrict__ p, float* __restrict__ r) {
    __shared__ ushort As[128 * LDB2];
    __shared__ ushort Bs[80 * LDB2];
    int tid = threadIdx.x;
    int wave = tid >> 6, lane = tid & 63;
    int row0 = blockIdx.x * 128;
    f32x4 acc[2][5] = {};
    for (int kk = 0; kk < 512; kk += 64) {
        #pragma unroll
        for (int i = 0; i < 4; ++i) {
            int c = tid + i * 256;
            int rr_ = c >> 3, ks = c & 7;
            int gr = row0 + rr_;
            int4 va = {0, 0, 0, 0};
            if (gr < N_NODES) va = *(const int4*)(hbf + (size_t)gr * 512 + kk + ks * 8);
            *(int4*)(As + rr_ * LDB2 + ks * 8) = va;
        }
        #pragma unroll
        for (int i = 0; i < 3; ++i) {
            int c = tid + i * 256;
            if (c < 640) {
                int rr_ = c >> 3, ks = c & 7;
                int4 vb = *(const int4*)(wt2 + (size_t)rr_ * 512 + kk + ks * 8);
                *(int4*)(Bs + rr_ * LDB2 + ks * 8) = vb;
            }
        }
        __syncthreads();
        #pragma unroll
        for (int kb = 0; kb < 64; kb += 32) {
            int ko = kb + (lane >> 4) * 8;
            bf16x8 af[2], bfr[5];
            #pragma unroll
            for (int m = 0; m < 2; ++m)
                af[m] = *(const bf16x8*)(As + (wave * 32 + m * 16 + (lane & 15)) * LDB2 + ko);
            #pragma unroll
            for (int n = 0; n < 5; ++n)
                bfr[n] = *(const bf16x8*)(Bs + (n * 16 + (lane & 15)) * LDB2 + ko);
            #pragma unroll
            for (int m = 0; m < 2; ++m)
                #pragma unroll
                for (int n = 0; n < 5; ++n)
                    acc[m][n] = __builtin_amdgcn_mfma_f32_16x16x32_bf16(af[m], bfr[n], acc[m][n], 0, 0, 0);
        }
        __syncthreads();
    }
    #pragma unroll
    for (int m = 0; m < 2; ++m) {
        #pragma unroll
        for (int j = 0; j < 4; ++j) {
            int grow = row0 + wave * 32 + m * 16 + (lane >> 4) * 4 + j;
            if (grow >= N_NODES) continue;
            #pragma unroll
            for (int n = 0; n < 5; ++n) {
                int col = n * 16 + (lane & 15);
                float v = acc[m][n][j];
                if (col < 40) p[(size_t)grow * 40 + col] = v;
                else          r[(size_t)grow * 40 + (col - 40)] = v;
            }
        }
    }
}

// out = log_softmax(mean_j p[src] + b2 + r)  one wave per node, lanes 0..39
__global__ void final_kernel(const float* __restrict__ p, const float* __restrict__ rr,
                             const float* __restrict__ b2,
                             const int* __restrict__ row_ptr, const int* __restrict__ csr_src,
                             float* __restrict__ out) {
    int wid = threadIdx.x >> 6;
    int lane = threadIdx.x & 63;
    int n = blockIdx.x * 4 + wid;
    if (n >= N_NODES) return;
    int beg = row_ptr[n], end = row_ptr[n + 1];
    float acc0 = 0.f, acc1 = 0.f;
    int e = beg;
    if (lane < OUT_DIM) {
        for (; e + 1 < end; e += 2) {
            int s0 = csr_src[e], s1 = csr_src[e + 1];
            acc0 += p[(size_t)s0 * OUT_DIM + lane];
            acc1 += p[(size_t)s1 * OUT_DIM + lane];
        }
        if (e < end) acc0 += p[(size_t)csr_src[e] * OUT_DIM + lane];
    }
    int d = end - beg; if (d < 1) d = 1;
    float inv = 1.0f / (float)d;
    float v = (lane < OUT_DIM)
                  ? ((acc0 + acc1) * inv + b2[lane] + rr[(size_t)n * OUT_DIM + lane])
                  : -INFINITY;
    float m = v;
    #pragma unroll
    for (int off = 32; off; off >>= 1) m = fmaxf(m, __shfl_xor(m, off));
    float ex = (lane < OUT_DIM) ? expf(v - m) : 0.f;
    float ssum = ex;
    #pragma unroll
    for (int off = 32; off; off >>= 1) ssum += __shfl_xor(ssum, off);
    if (lane < OUT_DIM) out[(size_t)n * OUT_DIM + lane] = (v - m) - logf(ssum);
}

extern "C" void kernel_launch(void* const* d_in, const int* in_sizes, int n_in,
                              void* d_out, int out_size, void* d_ws, size_t ws_size,
                              hipStream_t stream) {
    const float* x    = (const float*)d_in[0];
    const int*   edge = (const int*)d_in[1];
    const int*   srce = edge;
    const int*   dste = edge + N_EDGES;
    const float* w1l  = (const float*)d_in[2];
    const float* b1   = (const float*)d_in[3];
    const float* w1r  = (const float*)d_in[4];
    const float* w2l  = (const float*)d_in[5];
    const float* b2   = (const float*)d_in[6];
    const float* w2r  = (const float*)d_in[7];
    float* out = (float*)d_out;

    char* ws = (char*)d_ws;
    size_t off = 0;
    auto alloc = [&](size_t bytes) -> void* {
        void* ptr = ws + off;
        off = (off + bytes + 255) & ~(size_t)255;
        return ptr;
    };
    int* deg     = (int*)alloc((size_t)2 * N_NODES * 4);
    int* cursor  = deg + N_NODES;
    int* row_ptr = (int*)alloc((size_t)(N_NODES + 1) * 4);
    int* bsum    = (int*)alloc((size_t)NB_SCAN * 4);
    int* csr_src = (int*)alloc((size_t)N_EDGES * 4);
    ushort* abuf = (ushort*)alloc((size_t)N_NODES * 256 * 2);   // [agg|x] bf16
    ushort* wt   = (ushort*)alloc((size_t)512 * 256 * 2);       // [w1_l;w1_r]^T bf16
    ushort* wt2  = (ushort*)alloc((size_t)80 * 512 * 2);        // [w2_l|w2_r]^T bf16
    ushort* h    = (ushort*)alloc((size_t)N_NODES * HID * 2);   // h bf16
    float* p     = (float*)alloc((size_t)N_NODES * OUT_DIM * 4);
    float* rbuf  = (float*)alloc((size_t)N_NODES * OUT_DIM * 4);

    zero_ints<<<(2 * N_NODES + 255) / 256, 256, 0, stream>>>(deg, 2 * N_NODES);
    count_deg<<<(N_EDGES + 255) / 256, 256, 0, stream>>>(dste, deg);
    deg_block_sums<<<NB_SCAN, 256, 0, stream>>>(deg, bsum);
    scan_bsum<<<1, 256, 0, stream>>>(bsum);
    scan_fill<<<NB_SCAN, 256, 0, stream>>>(deg, bsum, row_ptr);
    fill_csr<<<(N_EDGES + 255) / 256, 256, 0, stream>>>(srce, dste, row_ptr, cursor, csr_src);
    cvt_x<<<(N_NODES * 32 + 255) / 256, 256, 0, stream>>>(x, abuf);
    cvt_w<<<(512 * 256 + 255) / 256, 256, 0, stream>>>(w1l, w1r, wt);
    cvt_w2<<<(80 * 512 + 255) / 256, 256, 0, stream>>>(w2l, w2r, wt2);
    agg_x<<<(N_NODES + 3) / 4, 256, 0, stream>>>(x, row_ptr, csr_src, abuf);
    gemm1_mfma<<<dim3((N_NODES + 127) / 128, 4), 256, 0, stream>>>(abuf, wt, b1, h);
    gemm2_mfma<<<(N_NODES + 127) / 128, 256, 0, stream>>>(h, wt2, p, rbuf);
    final_kernel<<<(N_NODES + 3) / 4, 256, 0, stream>>>(p, rbuf, b2, row_ptr, csr_src, out);
}

// Round 5
// 253.646 us; speedup vs baseline: 2.7141x; 1.1031x over previous
//
#include <hip/hip_runtime.h>
#include <math.h>

#define N_NODES 50000
#define N_EDGES 800000
#define IN_DIM 128
#define HID 512
#define OUT_DIM 40
#define NB_SCAN ((N_NODES + 255) / 256)   // 196

typedef __attribute__((ext_vector_type(8))) short bf16x8;
typedef __attribute__((ext_vector_type(4))) float f32x4;

__device__ __forceinline__ ushort f2bf(float f) {
    unsigned u = __float_as_uint(f);
    u += 0x7fff + ((u >> 16) & 1);   // round-to-nearest-even
    return (ushort)(u >> 16);
}

// async global->LDS, 16B per lane, dest = wave-uniform base + lane*16
__device__ __forceinline__ void gload_lds16(const ushort* g, ushort* l) {
    __builtin_amdgcn_global_load_lds(
        (__attribute__((address_space(1))) void*)g,
        (__attribute__((address_space(3))) void*)l, 16, 0, 0);
}

__global__ void zero_ints(int* __restrict__ a, int n) {
    int i = blockIdx.x * blockDim.x + threadIdx.x;
    if (i < n) a[i] = 0;
}

__global__ void count_deg(const int* __restrict__ dst, int* __restrict__ deg) {
    int e = blockIdx.x * blockDim.x + threadIdx.x;
    if (e < N_EDGES) atomicAdd(&deg[dst[e]], 1);
}

// --- 3-stage parallel exclusive scan: deg[50000] -> row_ptr[50001] ---
__global__ void deg_block_sums(const int* __restrict__ deg, int* __restrict__ bsum) {
    __shared__ int red[256];
    int tid = threadIdx.x;
    int i = blockIdx.x * 256 + tid;
    red[tid] = (i < N_NODES) ? deg[i] : 0;
    __syncthreads();
    #pragma unroll
    for (int off = 128; off; off >>= 1) {
        if (tid < off) red[tid] += red[tid + off];
        __syncthreads();
    }
    if (tid == 0) bsum[blockIdx.x] = red[0];
}

__global__ void scan_bsum(int* __restrict__ bsum) {
    __shared__ int s[256];
    int tid = threadIdx.x;
    int v = (tid < NB_SCAN) ? bsum[tid] : 0;
    s[tid] = v;
    __syncthreads();
    #pragma unroll
    for (int off = 1; off < 256; off <<= 1) {
        int add = (tid >= off) ? s[tid - off] : 0;
        __syncthreads();
        s[tid] += add;
        __syncthreads();
    }
    if (tid < NB_SCAN) bsum[tid] = s[tid] - v;   // exclusive
}

__global__ void scan_fill(const int* __restrict__ deg, const int* __restrict__ bsum,
                          int* __restrict__ row_ptr) {
    __shared__ int s[256];
    int tid = threadIdx.x;
    int i = blockIdx.x * 256 + tid;
    int v = (i < N_NODES) ? deg[i] : 0;
    s[tid] = v;
    __syncthreads();
    #pragma unroll
    for (int off = 1; off < 256; off <<= 1) {
        int add = (tid >= off) ? s[tid - off] : 0;
        __syncthreads();
        s[tid] += add;
        __syncthreads();
    }
    int excl = s[tid] - v + bsum[blockIdx.x];
    if (i < N_NODES) row_ptr[i] = excl;
    if (i == N_NODES - 1) row_ptr[N_NODES] = excl + v;
}

__global__ void fill_csr(const int* __restrict__ src, const int* __restrict__ dst,
                         const int* __restrict__ row_ptr, int* __restrict__ cursor,
                         int* __restrict__ csr_src) {
    int e = blockIdx.x * blockDim.x + threadIdx.x;
    if (e < N_EDGES) {
        int d = dst[e];
        int pos = atomicAdd(&cursor[d], 1);
        csr_src[row_ptr[d] + pos] = src[e];
    }
}

// one wave per node: mean of x[src] rows -> bf16 into abuf[n][0..127]
__global__ void agg_x(const float* __restrict__ x, const int* __restrict__ row_ptr,
                      const int* __restrict__ csr_src, ushort* __restrict__ abuf) {
    int wid = threadIdx.x >> 6;
    int lane = threadIdx.x & 63;
    int n = blockIdx.x * 4 + wid;
    if (n >= N_NODES) return;
    int beg = row_ptr[n], end = row_ptr[n + 1];
    int half = lane >> 5, l32 = lane & 31;
    float4 a0 = {0, 0, 0, 0}, a1 = {0, 0, 0, 0}, a2 = {0, 0, 0, 0}, a3 = {0, 0, 0, 0};
    int e = beg + half;
    for (; e + 6 < end; e += 8) {
        int s0 = csr_src[e], s1 = csr_src[e + 2], s2 = csr_src[e + 4], s3 = csr_src[e + 6];
        float4 v0 = *(const float4*)(x + (size_t)s0 * IN_DIM + l32 * 4);
        float4 v1 = *(const float4*)(x + (size_t)s1 * IN_DIM + l32 * 4);
        float4 v2 = *(const float4*)(x + (size_t)s2 * IN_DIM + l32 * 4);
        float4 v3 = *(const float4*)(x + (size_t)s3 * IN_DIM + l32 * 4);
        a0.x += v0.x; a0.y += v0.y; a0.z += v0.z; a0.w += v0.w;
        a1.x += v1.x; a1.y += v1.y; a1.z += v1.z; a1.w += v1.w;
        a2.x += v2.x; a2.y += v2.y; a2.z += v2.z; a2.w += v2.w;
        a3.x += v3.x; a3.y += v3.y; a3.z += v3.z; a3.w += v3.w;
    }
    for (; e < end; e += 2) {
        int s = csr_src[e];
        float4 v = *(const float4*)(x + (size_t)s * IN_DIM + l32 * 4);
        a0.x += v.x; a0.y += v.y; a0.z += v.z; a0.w += v.w;
    }
    a0.x += a1.x + a2.x + a3.x;
    a0.y += a1.y + a2.y + a3.y;
    a0.z += a1.z + a2.z + a3.z;
    a0.w += a1.w + a2.w + a3.w;
    a0.x += __shfl_xor(a0.x, 32);
    a0.y += __shfl_xor(a0.y, 32);
    a0.z += __shfl_xor(a0.z, 32);
    a0.w += __shfl_xor(a0.w, 32);
    int d = end - beg; if (d < 1) d = 1;
    float inv = 1.0f / (float)d;
    if (half == 0) {
        ushort4 o;
        o.x = f2bf(a0.x * inv); o.y = f2bf(a0.y * inv);
        o.z = f2bf(a0.z * inv); o.w = f2bf(a0.w * inv);
        *(ushort4*)(abuf + (size_t)n * 256 + l32 * 4) = o;
    }
}

// abuf[n][128..255] = bf16(x[n][:])
__global__ void cvt_x(const float* __restrict__ x, ushort* __restrict__ abuf) {
    int i = blockIdx.x * blockDim.x + threadIdx.x;
    if (i >= N_NODES * 32) return;
    int n = i >> 5, q = i & 31;
    float4 v = *(const float4*)(x + (size_t)n * 128 + q * 4);
    ushort4 o;
    o.x = f2bf(v.x); o.y = f2bf(v.y); o.z = f2bf(v.z); o.w = f2bf(v.w);
    *(ushort4*)(abuf + (size_t)n * 256 + 128 + q * 4) = o;
}

// wt[c][k] = bf16( k<128 ? w1_l[k][c] : w1_r[k-128][c] )   [512][256]
__global__ void cvt_w(const float* __restrict__ wl, const float* __restrict__ wr,
                      ushort* __restrict__ wt) {
    int i = blockIdx.x * blockDim.x + threadIdx.x;
    if (i >= 512 * 256) return;
    int k = i >> 9, c = i & 511;
    float v = (k < 128) ? wl[(size_t)k * 512 + c] : wr[(size_t)(k - 128) * 512 + c];
    wt[(size_t)c * 256 + k] = f2bf(v);
}

// wt2[c][k] = bf16( c<40 ? w2_l[k][c] : w2_r[k][c-40] )   [80][512]
__global__ void cvt_w2(const float* __restrict__ wl, const float* __restrict__ wr,
                       ushort* __restrict__ wt2) {
    int i = blockIdx.x * blockDim.x + threadIdx.x;
    if (i >= 80 * 512) return;
    int c = i >> 9, k = i & 511;
    float v = (c < 40) ? wl[(size_t)k * 40 + c] : wr[(size_t)k * 40 + (c - 40)];
    wt2[(size_t)c * 512 + k] = f2bf(v);
}

// h = relu(A @ WT^T + b)  A:[50000][256] bf16, WT:[512][256] bf16 -> h bf16
// BK=64, linear LDS [128][64] via global_load_lds, XOR swizzle slot^= (row&7)
__global__ __launch_bounds__(256) void gemm1_mfma(
    const ushort* __restrict__ A, const ushort* __restrict__ BT,
    const float* __restrict__ bias, ushort* __restrict__ h) {
    __shared__ ushort As[128 * 64];
    __shared__ ushort Bs[128 * 64];
    int tid = threadIdx.x;
    int wave = tid >> 6, lane = tid & 63;
    int wm = wave >> 1, wn = wave & 1;      // 2x2 waves, 64x64 each
    int row0 = blockIdx.x * 128;
    int col0 = blockIdx.y * 128;
    f32x4 acc[4][4] = {};
    for (int kk = 0; kk < 256; kk += 64) {
        // stage A (16KB = 16 chunks of 1KB) + B; source pre-swizzled (rule #21)
        #pragma unroll
        for (int c = 0; c < 4; ++c) {
            int ch = wave + c * 4;
            int o = ch * 1024 + lane * 16;      // linear LDS byte offset
            int row = o >> 7;                   // 128B per row
            int s = (o >> 4) & 7;               // 16B slot in row
            int ssrc = s ^ (row & 7);
            int gr = row0 + row; if (gr > N_NODES - 1) gr = N_NODES - 1;
            gload_lds16(A + (size_t)gr * 256 + kk + (ssrc << 3), As + ch * 512);
            int gc = col0 + row;
            gload_lds16(BT + (size_t)gc * 256 + kk + (ssrc << 3), Bs + ch * 512);
        }
        __syncthreads();
        #pragma unroll
        for (int kc = 0; kc < 2; ++kc) {
            int sbase = kc * 4 + (lane >> 4);
            bf16x8 af[4], bfr[4];
            #pragma unroll
            for (int m = 0; m < 4; ++m) {
                int row = wm * 64 + m * 16 + (lane & 15);
                af[m] = *(const bf16x8*)(As + row * 64 + ((sbase ^ (row & 7)) << 3));
            }
            #pragma unroll
            for (int n = 0; n < 4; ++n) {
                int row = wn * 64 + n * 16 + (lane & 15);
                bfr[n] = *(const bf16x8*)(Bs + row * 64 + ((sbase ^ (row & 7)) << 3));
            }
            #pragma unroll
            for (int m = 0; m < 4; ++m)
                #pragma unroll
                for (int n = 0; n < 4; ++n)
                    acc[m][n] = __builtin_amdgcn_mfma_f32_16x16x32_bf16(af[m], bfr[n], acc[m][n], 0, 0, 0);
        }
        __syncthreads();
    }
    #pragma unroll
    for (int m = 0; m < 4; ++m) {
        #pragma unroll
        for (int j = 0; j < 4; ++j) {
            int grow = row0 + wm * 64 + m * 16 + (lane >> 4) * 4 + j;
            if (grow >= N_NODES) continue;
            #pragma unroll
            for (int n = 0; n < 4; ++n) {
                int gcol = col0 + wn * 64 + n * 16 + (lane & 15);
                float v = acc[m][n][j] + bias[gcol];
                h[(size_t)grow * 512 + gcol] = f2bf(v > 0.f ? v : 0.f);
            }
        }
    }
}

// [p|r] = h @ wt2^T   h:[50000][512] bf16, wt2:[80][512] bf16
// same BK=64 swizzled global_load_lds structure
__global__ __launch_bounds__(256) void gemm2_mfma(
    const ushort* __restrict__ hbf, const ushort* __restrict__ wt2,
    float* __restrict__ p, float* __restrict__ r) {
    __shared__ ushort As[128 * 64];
    __shared__ ushort Bs[80 * 64];
    int tid = threadIdx.x;
    int wave = tid >> 6, lane = tid & 63;
    int row0 = blockIdx.x * 128;
    f32x4 acc[2][5] = {};
    for (int kk = 0; kk < 512; kk += 64) {
        #pragma unroll
        for (int c = 0; c < 4; ++c) {
            int ch = wave + c * 4;
            int o = ch * 1024 + lane * 16;
            int row = o >> 7;
            int s = (o >> 4) & 7;
            int ssrc = s ^ (row & 7);
            int gr = row0 + row; if (gr > N_NODES - 1) gr = N_NODES - 1;
            gload_lds16(hbf + (size_t)gr * 512 + kk + (ssrc << 3), As + ch * 512);
        }
        for (int ch = wave; ch < 10; ch += 4) {
            int o = ch * 1024 + lane * 16;
            int row = o >> 7;                  // 0..79
            int s = (o >> 4) & 7;
            int ssrc = s ^ (row & 7);
            gload_lds16(wt2 + (size_t)row * 512 + kk + (ssrc << 3), Bs + ch * 512);
        }
        __syncthreads();
        #pragma unroll
        for (int kc = 0; kc < 2; ++kc) {
            int sbase = kc * 4 + (lane >> 4);
            bf16x8 af[2], bfr[5];
            #pragma unroll
            for (int m = 0; m < 2; ++m) {
                int row = wave * 32 + m * 16 + (lane & 15);
                af[m] = *(const bf16x8*)(As + row * 64 + ((sbase ^ (row & 7)) << 3));
            }
            #pragma unroll
            for (int n = 0; n < 5; ++n) {
                int row = n * 16 + (lane & 15);
                bfr[n] = *(const bf16x8*)(Bs + row * 64 + ((sbase ^ (row & 7)) << 3));
            }
            #pragma unroll
            for (int m = 0; m < 2; ++m)
                #pragma unroll
                for (int n = 0; n < 5; ++n)
                    acc[m][n] = __builtin_amdgcn_mfma_f32_16x16x32_bf16(af[m], bfr[n], acc[m][n], 0, 0, 0);
        }
        __syncthreads();
    }
    #pragma unroll
    for (int m = 0; m < 2; ++m) {
        #pragma unroll
        for (int j = 0; j < 4; ++j) {
            int grow = row0 + wave * 32 + m * 16 + (lane >> 4) * 4 + j;
            if (grow >= N_NODES) continue;
            #pragma unroll
            for (int n = 0; n < 5; ++n) {
                int col = n * 16 + (lane & 15);
                float v = acc[m][n][j];
                if (col < 40) p[(size_t)grow * 40 + col] = v;
                else          r[(size_t)grow * 40 + (col - 40)] = v;
            }
        }
    }
}

// out = log_softmax(mean_j p[src] + b2 + r)  one wave per node, lanes 0..39
__global__ void final_kernel(const float* __restrict__ p, const float* __restrict__ rr,
                             const float* __restrict__ b2,
                             const int* __restrict__ row_ptr, const int* __restrict__ csr_src,
                             float* __restrict__ out) {
    int wid = threadIdx.x >> 6;
    int lane = threadIdx.x & 63;
    int n = blockIdx.x * 4 + wid;
    if (n >= N_NODES) return;
    int beg = row_ptr[n], end = row_ptr[n + 1];
    float acc0 = 0.f, acc1 = 0.f;
    int e = beg;
    if (lane < OUT_DIM) {
        for (; e + 1 < end; e += 2) {
            int s0 = csr_src[e], s1 = csr_src[e + 1];
            acc0 += p[(size_t)s0 * OUT_DIM + lane];
            acc1 += p[(size_t)s1 * OUT_DIM + lane];
        }
        if (e < end) acc0 += p[(size_t)csr_src[e] * OUT_DIM + lane];
    }
    int d = end - beg; if (d < 1) d = 1;
    float inv = 1.0f / (float)d;
    float v = (lane < OUT_DIM)
                  ? ((acc0 + acc1) * inv + b2[lane] + rr[(size_t)n * OUT_DIM + lane])
                  : -INFINITY;
    float m = v;
    #pragma unroll
    for (int off = 32; off; off >>= 1) m = fmaxf(m, __shfl_xor(m, off));
    float ex = (lane < OUT_DIM) ? expf(v - m) : 0.f;
    float ssum = ex;
    #pragma unroll
    for (int off = 32; off; off >>= 1) ssum += __shfl_xor(ssum, off);
    if (lane < OUT_DIM) out[(size_t)n * OUT_DIM + lane] = (v - m) - logf(ssum);
}

extern "C" void kernel_launch(void* const* d_in, const int* in_sizes, int n_in,
                              void* d_out, int out_size, void* d_ws, size_t ws_size,
                              hipStream_t stream) {
    const float* x    = (const float*)d_in[0];
    const int*   edge = (const int*)d_in[1];
    const int*   srce = edge;
    const int*   dste = edge + N_EDGES;
    const float* w1l  = (const float*)d_in[2];
    const float* b1   = (const float*)d_in[3];
    const float* w1r  = (const float*)d_in[4];
    const float* w2l  = (const float*)d_in[5];
    const float* b2   = (const float*)d_in[6];
    const float* w2r  = (const float*)d_in[7];
    float* out = (float*)d_out;

    char* ws = (char*)d_ws;
    size_t off = 0;
    auto alloc = [&](size_t bytes) -> void* {
        void* ptr = ws + off;
        off = (off + bytes + 255) & ~(size_t)255;
        return ptr;
    };
    int* deg     = (int*)alloc((size_t)2 * N_NODES * 4);
    int* cursor  = deg + N_NODES;
    int* row_ptr = (int*)alloc((size_t)(N_NODES + 1) * 4);
    int* bsum    = (int*)alloc((size_t)NB_SCAN * 4);
    int* csr_src = (int*)alloc((size_t)N_EDGES * 4);
    ushort* abuf = (ushort*)alloc((size_t)N_NODES * 256 * 2);   // [agg|x] bf16
    ushort* wt   = (ushort*)alloc((size_t)512 * 256 * 2);       // [w1_l;w1_r]^T bf16
    ushort* wt2  = (ushort*)alloc((size_t)80 * 512 * 2);        // [w2_l|w2_r]^T bf16
    ushort* h    = (ushort*)alloc((size_t)N_NODES * HID * 2);   // h bf16
    float* p     = (float*)alloc((size_t)N_NODES * OUT_DIM * 4);
    float* rbuf  = (float*)alloc((size_t)N_NODES * OUT_DIM * 4);

    zero_ints<<<(2 * N_NODES + 255) / 256, 256, 0, stream>>>(deg, 2 * N_NODES);
    count_deg<<<(N_EDGES + 255) / 256, 256, 0, stream>>>(dste, deg);
    deg_block_sums<<<NB_SCAN, 256, 0, stream>>>(deg, bsum);
    scan_bsum<<<1, 256, 0, stream>>>(bsum);
    scan_fill<<<NB_SCAN, 256, 0, stream>>>(deg, bsum, row_ptr);
    fill_csr<<<(N_EDGES + 255) / 256, 256, 0, stream>>>(srce, dste, row_ptr, cursor, csr_src);
    cvt_x<<<(N_NODES * 32 + 255) / 256, 256, 0, stream>>>(x, abuf);
    cvt_w<<<(512 * 256 + 255) / 256, 256, 0, stream>>>(w1l, w1r, wt);
    cvt_w2<<<(80 * 512 + 255) / 256, 256, 0, stream>>>(w2l, w2r, wt2);
    agg_x<<<(N_NODES + 3) / 4, 256, 0, stream>>>(x, row_ptr, csr_src, abuf);
    gemm1_mfma<<<dim3((N_NODES + 127) / 128, 4), 256, 0, stream>>>(abuf, wt, b1, h);
    gemm2_mfma<<<(N_NODES + 127) / 128, 256, 0, stream>>>(h, wt2, p, rbuf);
    final_kernel<<<(N_NODES + 3) / 4, 256, 0, stream>>>(p, rbuf, b2, row_ptr, csr_src, out);
}

// Round 6
// 226.806 us; speedup vs baseline: 3.0352x; 1.1183x over previous
//
#include <hip/hip_runtime.h>
#include <math.h>

#define N_NODES 50000
#define N_EDGES 800000
#define IN_DIM 128
#define HID 512
#define OUT_DIM 40
#define NB_SCAN ((N_NODES + 255) / 256)   // 196

typedef __attribute__((ext_vector_type(8))) short bf16x8;
typedef __attribute__((ext_vector_type(4))) float f32x4;

__device__ __forceinline__ ushort f2bf(float f) {
    unsigned u = __float_as_uint(f);
    u += 0x7fff + ((u >> 16) & 1);   // round-to-nearest-even
    return (ushort)(u >> 16);
}

__device__ __forceinline__ float bf2f(ushort u) {
    return __uint_as_float(((unsigned)u) << 16);
}

// async global->LDS, 16B per lane, dest = wave-uniform base + lane*16
__device__ __forceinline__ void gload_lds16(const ushort* g, ushort* l) {
    __builtin_amdgcn_global_load_lds(
        (__attribute__((address_space(1))) void*)g,
        (__attribute__((address_space(3))) void*)l, 16, 0, 0);
}

__global__ void zero_ints(int* __restrict__ a, int n) {
    int i = blockIdx.x * blockDim.x + threadIdx.x;
    if (i < n) a[i] = 0;
}

__global__ void count_deg(const int* __restrict__ dst, int* __restrict__ deg) {
    int e = blockIdx.x * blockDim.x + threadIdx.x;
    if (e < N_EDGES) atomicAdd(&deg[dst[e]], 1);
}

// --- 3-stage parallel exclusive scan: deg[50000] -> row_ptr[50001] ---
__global__ void deg_block_sums(const int* __restrict__ deg, int* __restrict__ bsum) {
    __shared__ int red[256];
    int tid = threadIdx.x;
    int i = blockIdx.x * 256 + tid;
    red[tid] = (i < N_NODES) ? deg[i] : 0;
    __syncthreads();
    #pragma unroll
    for (int off = 128; off; off >>= 1) {
        if (tid < off) red[tid] += red[tid + off];
        __syncthreads();
    }
    if (tid == 0) bsum[blockIdx.x] = red[0];
}

__global__ void scan_bsum(int* __restrict__ bsum) {
    __shared__ int s[256];
    int tid = threadIdx.x;
    int v = (tid < NB_SCAN) ? bsum[tid] : 0;
    s[tid] = v;
    __syncthreads();
    #pragma unroll
    for (int off = 1; off < 256; off <<= 1) {
        int add = (tid >= off) ? s[tid - off] : 0;
        __syncthreads();
        s[tid] += add;
        __syncthreads();
    }
    if (tid < NB_SCAN) bsum[tid] = s[tid] - v;   // exclusive
}

__global__ void scan_fill(const int* __restrict__ deg, const int* __restrict__ bsum,
                          int* __restrict__ row_ptr) {
    __shared__ int s[256];
    int tid = threadIdx.x;
    int i = blockIdx.x * 256 + tid;
    int v = (i < N_NODES) ? deg[i] : 0;
    s[tid] = v;
    __syncthreads();
    #pragma unroll
    for (int off = 1; off < 256; off <<= 1) {
        int add = (tid >= off) ? s[tid - off] : 0;
        __syncthreads();
        s[tid] += add;
        __syncthreads();
    }
    int excl = s[tid] - v + bsum[blockIdx.x];
    if (i < N_NODES) row_ptr[i] = excl;
    if (i == N_NODES - 1) row_ptr[N_NODES] = excl + v;
}

__global__ void fill_csr(const int* __restrict__ src, const int* __restrict__ dst,
                         const int* __restrict__ row_ptr, int* __restrict__ cursor,
                         int* __restrict__ csr_src) {
    int e = blockIdx.x * blockDim.x + threadIdx.x;
    if (e < N_EDGES) {
        int d = dst[e];
        int pos = atomicAdd(&cursor[d], 1);
        csr_src[row_ptr[d] + pos] = src[e];
    }
}

// abuf[n][128..255] = bf16(x[n][:])  (must run BEFORE agg_x: agg gathers from it)
__global__ void cvt_x(const float* __restrict__ x, ushort* __restrict__ abuf) {
    int i = blockIdx.x * blockDim.x + threadIdx.x;
    if (i >= N_NODES * 32) return;
    int n = i >> 5, q = i & 31;
    float4 v = *(const float4*)(x + (size_t)n * 128 + q * 4);
    ushort4 o;
    o.x = f2bf(v.x); o.y = f2bf(v.y); o.z = f2bf(v.z); o.w = f2bf(v.w);
    *(ushort4*)(abuf + (size_t)n * 256 + 128 + q * 4) = o;
}

// one wave per node: mean of bf16-x[src] rows (from abuf x-half, 256B/row)
// half-wave per edge (32 lanes x ushort4 = 256B row), 4 rows in flight
__global__ void agg_x(const int* __restrict__ row_ptr,
                      const int* __restrict__ csr_src, ushort* __restrict__ abuf) {
    int wid = threadIdx.x >> 6;
    int lane = threadIdx.x & 63;
    int n = blockIdx.x * 4 + wid;
    if (n >= N_NODES) return;
    int beg = row_ptr[n], end = row_ptr[n + 1];
    int half = lane >> 5, l32 = lane & 31;
    const ushort* xb = abuf + 128;   // x-half of each 256-elem row
    float a0 = 0, a1 = 0, a2 = 0, a3 = 0;   // 4 features per lane
    float b0 = 0, b1 = 0, b2_ = 0, b3 = 0;  // second edge-in-flight accum
    int e = beg + half;
    for (; e + 2 < end; e += 4) {
        int s0 = csr_src[e], s1 = csr_src[e + 2];
        ushort4 v0 = *(const ushort4*)(xb + (size_t)s0 * 256 + l32 * 4);
        ushort4 v1 = *(const ushort4*)(xb + (size_t)s1 * 256 + l32 * 4);
        a0 += bf2f(v0.x); a1 += bf2f(v0.y); a2 += bf2f(v0.z); a3 += bf2f(v0.w);
        b0 += bf2f(v1.x); b1 += bf2f(v1.y); b2_ += bf2f(v1.z); b3 += bf2f(v1.w);
    }
    if (e < end) {
        int s = csr_src[e];
        ushort4 v = *(const ushort4*)(xb + (size_t)s * 256 + l32 * 4);
        a0 += bf2f(v.x); a1 += bf2f(v.y); a2 += bf2f(v.z); a3 += bf2f(v.w);
    }
    a0 += b0; a1 += b1; a2 += b2_; a3 += b3;
    a0 += __shfl_xor(a0, 32);
    a1 += __shfl_xor(a1, 32);
    a2 += __shfl_xor(a2, 32);
    a3 += __shfl_xor(a3, 32);
    int d = end - beg; if (d < 1) d = 1;
    float inv = 1.0f / (float)d;
    if (half == 0) {
        ushort4 o;
        o.x = f2bf(a0 * inv); o.y = f2bf(a1 * inv);
        o.z = f2bf(a2 * inv); o.w = f2bf(a3 * inv);
        *(ushort4*)(abuf + (size_t)n * 256 + l32 * 4) = o;
    }
}

// wt[c][k] = bf16( k<128 ? w1_l[k][c] : w1_r[k-128][c] )   [512][256]
__global__ void cvt_w(const float* __restrict__ wl, const float* __restrict__ wr,
                      ushort* __restrict__ wt) {
    int i = blockIdx.x * blockDim.x + threadIdx.x;
    if (i >= 512 * 256) return;
    int k = i >> 9, c = i & 511;
    float v = (k < 128) ? wl[(size_t)k * 512 + c] : wr[(size_t)(k - 128) * 512 + c];
    wt[(size_t)c * 256 + k] = f2bf(v);
}

// wt2[c][k] = bf16( c<40 ? w2_l[k][c] : w2_r[k][c-40] )   [80][512]
__global__ void cvt_w2(const float* __restrict__ wl, const float* __restrict__ wr,
                       ushort* __restrict__ wt2) {
    int i = blockIdx.x * blockDim.x + threadIdx.x;
    if (i >= 80 * 512) return;
    int c = i >> 9, k = i & 511;
    float v = (c < 40) ? wl[(size_t)k * 40 + c] : wr[(size_t)k * 40 + (c - 40)];
    wt2[(size_t)c * 512 + k] = f2bf(v);
}

// h = relu(A @ WT^T + b)  A:[50000][256] bf16, WT:[512][256] bf16 -> h bf16
// BK=64, linear LDS [128][64] via global_load_lds, XOR swizzle slot^= (row&7)
__global__ __launch_bounds__(256) void gemm1_mfma(
    const ushort* __restrict__ A, const ushort* __restrict__ BT,
    const float* __restrict__ bias, ushort* __restrict__ h) {
    __shared__ ushort As[128 * 64];
    __shared__ ushort Bs[128 * 64];
    int tid = threadIdx.x;
    int wave = tid >> 6, lane = tid & 63;
    int wm = wave >> 1, wn = wave & 1;      // 2x2 waves, 64x64 each
    int row0 = blockIdx.x * 128;
    int col0 = blockIdx.y * 128;
    f32x4 acc[4][4] = {};
    for (int kk = 0; kk < 256; kk += 64) {
        #pragma unroll
        for (int c = 0; c < 4; ++c) {
            int ch = wave + c * 4;
            int o = ch * 1024 + lane * 16;      // linear LDS byte offset
            int row = o >> 7;                   // 128B per row
            int s = (o >> 4) & 7;               // 16B slot in row
            int ssrc = s ^ (row & 7);
            int gr = row0 + row; if (gr > N_NODES - 1) gr = N_NODES - 1;
            gload_lds16(A + (size_t)gr * 256 + kk + (ssrc << 3), As + ch * 512);
            int gc = col0 + row;
            gload_lds16(BT + (size_t)gc * 256 + kk + (ssrc << 3), Bs + ch * 512);
        }
        __syncthreads();
        #pragma unroll
        for (int kc = 0; kc < 2; ++kc) {
            int sbase = kc * 4 + (lane >> 4);
            bf16x8 af[4], bfr[4];
            #pragma unroll
            for (int m = 0; m < 4; ++m) {
                int row = wm * 64 + m * 16 + (lane & 15);
                af[m] = *(const bf16x8*)(As + row * 64 + ((sbase ^ (row & 7)) << 3));
            }
            #pragma unroll
            for (int n = 0; n < 4; ++n) {
                int row = wn * 64 + n * 16 + (lane & 15);
                bfr[n] = *(const bf16x8*)(Bs + row * 64 + ((sbase ^ (row & 7)) << 3));
            }
            #pragma unroll
            for (int m = 0; m < 4; ++m)
                #pragma unroll
                for (int n = 0; n < 4; ++n)
                    acc[m][n] = __builtin_amdgcn_mfma_f32_16x16x32_bf16(af[m], bfr[n], acc[m][n], 0, 0, 0);
        }
        __syncthreads();
    }
    #pragma unroll
    for (int m = 0; m < 4; ++m) {
        #pragma unroll
        for (int j = 0; j < 4; ++j) {
            int grow = row0 + wm * 64 + m * 16 + (lane >> 4) * 4 + j;
            if (grow >= N_NODES) continue;
            #pragma unroll
            for (int n = 0; n < 4; ++n) {
                int gcol = col0 + wn * 64 + n * 16 + (lane & 15);
                float v = acc[m][n][j] + bias[gcol];
                h[(size_t)grow * 512 + gcol] = f2bf(v > 0.f ? v : 0.f);
            }
        }
    }
}

// [p|r] = h @ wt2^T   h:[50000][512] bf16, wt2:[80][512] bf16
// p stored bf16 (gathered by final), r stored fp32 (node-local)
__global__ __launch_bounds__(256) void gemm2_mfma(
    const ushort* __restrict__ hbf, const ushort* __restrict__ wt2,
    ushort* __restrict__ p, float* __restrict__ r) {
    __shared__ ushort As[128 * 64];
    __shared__ ushort Bs[80 * 64];
    int tid = threadIdx.x;
    int wave = tid >> 6, lane = tid & 63;
    int row0 = blockIdx.x * 128;
    f32x4 acc[2][5] = {};
    for (int kk = 0; kk < 512; kk += 64) {
        #pragma unroll
        for (int c = 0; c < 4; ++c) {
            int ch = wave + c * 4;
            int o = ch * 1024 + lane * 16;
            int row = o >> 7;
            int s = (o >> 4) & 7;
            int ssrc = s ^ (row & 7);
            int gr = row0 + row; if (gr > N_NODES - 1) gr = N_NODES - 1;
            gload_lds16(hbf + (size_t)gr * 512 + kk + (ssrc << 3), As + ch * 512);
        }
        for (int ch = wave; ch < 10; ch += 4) {
            int o = ch * 1024 + lane * 16;
            int row = o >> 7;                  // 0..79
            int s = (o >> 4) & 7;
            int ssrc = s ^ (row & 7);
            gload_lds16(wt2 + (size_t)row * 512 + kk + (ssrc << 3), Bs + ch * 512);
        }
        __syncthreads();
        #pragma unroll
        for (int kc = 0; kc < 2; ++kc) {
            int sbase = kc * 4 + (lane >> 4);
            bf16x8 af[2], bfr[5];
            #pragma unroll
            for (int m = 0; m < 2; ++m) {
                int row = wave * 32 + m * 16 + (lane & 15);
                af[m] = *(const bf16x8*)(As + row * 64 + ((sbase ^ (row & 7)) << 3));
            }
            #pragma unroll
            for (int n = 0; n < 5; ++n) {
                int row = n * 16 + (lane & 15);
                bfr[n] = *(const bf16x8*)(Bs + row * 64 + ((sbase ^ (row & 7)) << 3));
            }
            #pragma unroll
            for (int m = 0; m < 2; ++m)
                #pragma unroll
                for (int n = 0; n < 5; ++n)
                    acc[m][n] = __builtin_amdgcn_mfma_f32_16x16x32_bf16(af[m], bfr[n], acc[m][n], 0, 0, 0);
        }
        __syncthreads();
    }
    #pragma unroll
    for (int m = 0; m < 2; ++m) {
        #pragma unroll
        for (int j = 0; j < 4; ++j) {
            int grow = row0 + wave * 32 + m * 16 + (lane >> 4) * 4 + j;
            if (grow >= N_NODES) continue;
            #pragma unroll
            for (int n = 0; n < 5; ++n) {
                int col = n * 16 + (lane & 15);
                float v = acc[m][n][j];
                if (col < 40) p[(size_t)grow * 40 + col] = f2bf(v);
                else          r[(size_t)grow * 40 + (col - 40)] = v;
            }
        }
    }
}

// out = log_softmax(mean_j p[src] + b2 + r)  one wave per node, lanes 0..39
// p is bf16 (4MB, per-XCD-L2-resident); 4 edges in flight
__global__ void final_kernel(const ushort* __restrict__ p, const float* __restrict__ rr,
                             const float* __restrict__ b2,
                             const int* __restrict__ row_ptr, const int* __restrict__ csr_src,
                             float* __restrict__ out) {
    int wid = threadIdx.x >> 6;
    int lane = threadIdx.x & 63;
    int n = blockIdx.x * 4 + wid;
    if (n >= N_NODES) return;
    int beg = row_ptr[n], end = row_ptr[n + 1];
    float acc0 = 0.f, acc1 = 0.f, acc2 = 0.f, acc3 = 0.f;
    int e = beg;
    if (lane < OUT_DIM) {
        for (; e + 3 < end; e += 4) {
            int s0 = csr_src[e], s1 = csr_src[e + 1];
            int s2 = csr_src[e + 2], s3 = csr_src[e + 3];
            acc0 += bf2f(p[(size_t)s0 * OUT_DIM + lane]);
            acc1 += bf2f(p[(size_t)s1 * OUT_DIM + lane]);
            acc2 += bf2f(p[(size_t)s2 * OUT_DIM + lane]);
            acc3 += bf2f(p[(size_t)s3 * OUT_DIM + lane]);
        }
        for (; e < end; ++e)
            acc0 += bf2f(p[(size_t)csr_src[e] * OUT_DIM + lane]);
    }
    int d = end - beg; if (d < 1) d = 1;
    float inv = 1.0f / (float)d;
    float v = (lane < OUT_DIM)
                  ? ((acc0 + acc1 + acc2 + acc3) * inv + b2[lane] + rr[(size_t)n * OUT_DIM + lane])
                  : -INFINITY;
    float m = v;
    #pragma unroll
    for (int off = 32; off; off >>= 1) m = fmaxf(m, __shfl_xor(m, off));
    float ex = (lane < OUT_DIM) ? expf(v - m) : 0.f;
    float ssum = ex;
    #pragma unroll
    for (int off = 32; off; off >>= 1) ssum += __shfl_xor(ssum, off);
    if (lane < OUT_DIM) out[(size_t)n * OUT_DIM + lane] = (v - m) - logf(ssum);
}

extern "C" void kernel_launch(void* const* d_in, const int* in_sizes, int n_in,
                              void* d_out, int out_size, void* d_ws, size_t ws_size,
                              hipStream_t stream) {
    const float* x    = (const float*)d_in[0];
    const int*   edge = (const int*)d_in[1];
    const int*   srce = edge;
    const int*   dste = edge + N_EDGES;
    const float* w1l  = (const float*)d_in[2];
    const float* b1   = (const float*)d_in[3];
    const float* w1r  = (const float*)d_in[4];
    const float* w2l  = (const float*)d_in[5];
    const float* b2   = (const float*)d_in[6];
    const float* w2r  = (const float*)d_in[7];
    float* out = (float*)d_out;

    char* ws = (char*)d_ws;
    size_t off = 0;
    auto alloc = [&](size_t bytes) -> void* {
        void* ptr = ws + off;
        off = (off + bytes + 255) & ~(size_t)255;
        return ptr;
    };
    int* deg     = (int*)alloc((size_t)2 * N_NODES * 4);
    int* cursor  = deg + N_NODES;
    int* row_ptr = (int*)alloc((size_t)(N_NODES + 1) * 4);
    int* bsum    = (int*)alloc((size_t)NB_SCAN * 4);
    int* csr_src = (int*)alloc((size_t)N_EDGES * 4);
    ushort* abuf = (ushort*)alloc((size_t)N_NODES * 256 * 2);   // [agg|x] bf16
    ushort* wt   = (ushort*)alloc((size_t)512 * 256 * 2);       // [w1_l;w1_r]^T bf16
    ushort* wt2  = (ushort*)alloc((size_t)80 * 512 * 2);        // [w2_l|w2_r]^T bf16
    ushort* h    = (ushort*)alloc((size_t)N_NODES * HID * 2);   // h bf16
    ushort* p    = (ushort*)alloc((size_t)N_NODES * OUT_DIM * 2);  // p bf16
    float* rbuf  = (float*)alloc((size_t)N_NODES * OUT_DIM * 4);

    zero_ints<<<(2 * N_NODES + 255) / 256, 256, 0, stream>>>(deg, 2 * N_NODES);
    count_deg<<<(N_EDGES + 255) / 256, 256, 0, stream>>>(dste, deg);
    deg_block_sums<<<NB_SCAN, 256, 0, stream>>>(deg, bsum);
    scan_bsum<<<1, 256, 0, stream>>>(bsum);
    scan_fill<<<NB_SCAN, 256, 0, stream>>>(deg, bsum, row_ptr);
    fill_csr<<<(N_EDGES + 255) / 256, 256, 0, stream>>>(srce, dste, row_ptr, cursor, csr_src);
    cvt_x<<<(N_NODES * 32 + 255) / 256, 256, 0, stream>>>(x, abuf);
    cvt_w<<<(512 * 256 + 255) / 256, 256, 0, stream>>>(w1l, w1r, wt);
    cvt_w2<<<(80 * 512 + 255) / 256, 256, 0, stream>>>(w2l, w2r, wt2);
    agg_x<<<(N_NODES + 3) / 4, 256, 0, stream>>>(row_ptr, csr_src, abuf);
    gemm1_mfma<<<dim3((N_NODES + 127) / 128, 4), 256, 0, stream>>>(abuf, wt, b1, h);
    gemm2_mfma<<<(N_NODES + 127) / 128, 256, 0, stream>>>(h, wt2, p, rbuf);
    final_kernel<<<(N_NODES + 3) / 4, 256, 0, stream>>>(p, rbuf, b2, row_ptr, csr_src, out);
}

// Round 7
// 224.475 us; speedup vs baseline: 3.0668x; 1.0104x over previous
//
#include <hip/hip_runtime.h>
#include <math.h>

#define N_NODES 50000
#define N_EDGES 800000
#define IN_DIM 128
#define HID 512
#define OUT_DIM 40
#define NB_SCAN ((N_NODES + 255) / 256)   // 196
#define NRANGE 8
#define RANGE_SZ ((N_NODES + NRANGE - 1) / NRANGE)   // 6250
#define NCHUNK 64

typedef __attribute__((ext_vector_type(8))) short bf16x8;
typedef __attribute__((ext_vector_type(4))) float f32x4;

__device__ __forceinline__ ushort f2bf(float f) {
    unsigned u = __float_as_uint(f);
    u += 0x7fff + ((u >> 16) & 1);   // round-to-nearest-even
    return (ushort)(u >> 16);
}

__device__ __forceinline__ float bf2f(ushort u) {
    return __uint_as_float(((unsigned)u) << 16);
}

// async global->LDS, 16B per lane, dest = wave-uniform base + lane*16
__device__ __forceinline__ void gload_lds16(const ushort* g, ushort* l) {
    __builtin_amdgcn_global_load_lds(
        (__attribute__((address_space(1))) void*)g,
        (__attribute__((address_space(3))) void*)l, 16, 0, 0);
}

__global__ void zero_ints(int* __restrict__ a, int n) {
    int i = blockIdx.x * blockDim.x + threadIdx.x;
    if (i < n) a[i] = 0;
}

// XCD-range-partitioned histogram: block (range = b&7, chunk = b>>3)
// streams its edge chunk, counts only dst in its node range -> L2-local atomics
__global__ void count_deg_part(const int* __restrict__ dst, int* __restrict__ deg) {
    int range = blockIdx.x & (NRANGE - 1);
    int chunk = blockIdx.x >> 3;
    int lo = range * RANGE_SZ;
    int hi = lo + RANGE_SZ; if (hi > N_NODES) hi = N_NODES;
    const int per = (N_EDGES + NCHUNK - 1) / NCHUNK;
    int beg = chunk * per;
    int end = beg + per; if (end > N_EDGES) end = N_EDGES;
    for (int e = beg + threadIdx.x; e < end; e += 256) {
        int d = dst[e];
        if (d >= lo && d < hi) atomicAdd(&deg[d], 1);
    }
}

// --- 3-stage parallel exclusive scan: deg[50000] -> row_ptr[50001] ---
__global__ void deg_block_sums(const int* __restrict__ deg, int* __restrict__ bsum) {
    __shared__ int red[256];
    int tid = threadIdx.x;
    int i = blockIdx.x * 256 + tid;
    red[tid] = (i < N_NODES) ? deg[i] : 0;
    __syncthreads();
    #pragma unroll
    for (int off = 128; off; off >>= 1) {
        if (tid < off) red[tid] += red[tid + off];
        __syncthreads();
    }
    if (tid == 0) bsum[blockIdx.x] = red[0];
}

__global__ void scan_bsum(int* __restrict__ bsum) {
    __shared__ int s[256];
    int tid = threadIdx.x;
    int v = (tid < NB_SCAN) ? bsum[tid] : 0;
    s[tid] = v;
    __syncthreads();
    #pragma unroll
    for (int off = 1; off < 256; off <<= 1) {
        int add = (tid >= off) ? s[tid - off] : 0;
        __syncthreads();
        s[tid] += add;
        __syncthreads();
    }
    if (tid < NB_SCAN) bsum[tid] = s[tid] - v;   // exclusive
}

__global__ void scan_fill(const int* __restrict__ deg, const int* __restrict__ bsum,
                          int* __restrict__ row_ptr) {
    __shared__ int s[256];
    int tid = threadIdx.x;
    int i = blockIdx.x * 256 + tid;
    int v = (i < N_NODES) ? deg[i] : 0;
    s[tid] = v;
    __syncthreads();
    #pragma unroll
    for (int off = 1; off < 256; off <<= 1) {
        int add = (tid >= off) ? s[tid - off] : 0;
        __syncthreads();
        s[tid] += add;
        __syncthreads();
    }
    int excl = s[tid] - v + bsum[blockIdx.x];
    if (i < N_NODES) row_ptr[i] = excl;
    if (i == N_NODES - 1) row_ptr[N_NODES] = excl + v;
}

// XCD-range-partitioned CSR fill: scattered cursor atomics + csr stores stay
// within one node-range slice (~400KB) owned by one XCD's L2
__global__ void fill_csr_part(const int* __restrict__ src, const int* __restrict__ dst,
                              const int* __restrict__ row_ptr, int* __restrict__ cursor,
                              int* __restrict__ csr_src) {
    int range = blockIdx.x & (NRANGE - 1);
    int chunk = blockIdx.x >> 3;
    int lo = range * RANGE_SZ;
    int hi = lo + RANGE_SZ; if (hi > N_NODES) hi = N_NODES;
    const int per = (N_EDGES + NCHUNK - 1) / NCHUNK;
    int beg = chunk * per;
    int end = beg + per; if (end > N_EDGES) end = N_EDGES;
    for (int e = beg + threadIdx.x; e < end; e += 256) {
        int d = dst[e];
        if (d >= lo && d < hi) {
            int pos = atomicAdd(&cursor[d], 1);
            csr_src[row_ptr[d] + pos] = src[e];
        }
    }
}

// abuf[n][128..255] = bf16(x[n][:])  (must run BEFORE agg_x: agg gathers from it)
__global__ void cvt_x(const float* __restrict__ x, ushort* __restrict__ abuf) {
    int i = blockIdx.x * blockDim.x + threadIdx.x;
    if (i >= N_NODES * 32) return;
    int n = i >> 5, q = i & 31;
    float4 v = *(const float4*)(x + (size_t)n * 128 + q * 4);
    ushort4 o;
    o.x = f2bf(v.x); o.y = f2bf(v.y); o.z = f2bf(v.z); o.w = f2bf(v.w);
    *(ushort4*)(abuf + (size_t)n * 256 + 128 + q * 4) = o;
}

// one wave per node: mean of bf16-x[src] rows (from abuf x-half, 256B/row)
__global__ void agg_x(const int* __restrict__ row_ptr,
                      const int* __restrict__ csr_src, ushort* __restrict__ abuf) {
    int wid = threadIdx.x >> 6;
    int lane = threadIdx.x & 63;
    int n = blockIdx.x * 4 + wid;
    if (n >= N_NODES) return;
    int beg = row_ptr[n], end = row_ptr[n + 1];
    int half = lane >> 5, l32 = lane & 31;
    const ushort* xb = abuf + 128;   // x-half of each 256-elem row
    float a0 = 0, a1 = 0, a2 = 0, a3 = 0;
    float b0 = 0, b1 = 0, b2_ = 0, b3 = 0;
    int e = beg + half;
    for (; e + 2 < end; e += 4) {
        int s0 = csr_src[e], s1 = csr_src[e + 2];
        ushort4 v0 = *(const ushort4*)(xb + (size_t)s0 * 256 + l32 * 4);
        ushort4 v1 = *(const ushort4*)(xb + (size_t)s1 * 256 + l32 * 4);
        a0 += bf2f(v0.x); a1 += bf2f(v0.y); a2 += bf2f(v0.z); a3 += bf2f(v0.w);
        b0 += bf2f(v1.x); b1 += bf2f(v1.y); b2_ += bf2f(v1.z); b3 += bf2f(v1.w);
    }
    if (e < end) {
        int s = csr_src[e];
        ushort4 v = *(const ushort4*)(xb + (size_t)s * 256 + l32 * 4);
        a0 += bf2f(v.x); a1 += bf2f(v.y); a2 += bf2f(v.z); a3 += bf2f(v.w);
    }
    a0 += b0; a1 += b1; a2 += b2_; a3 += b3;
    a0 += __shfl_xor(a0, 32);
    a1 += __shfl_xor(a1, 32);
    a2 += __shfl_xor(a2, 32);
    a3 += __shfl_xor(a3, 32);
    int d = end - beg; if (d < 1) d = 1;
    float inv = 1.0f / (float)d;
    if (half == 0) {
        ushort4 o;
        o.x = f2bf(a0 * inv); o.y = f2bf(a1 * inv);
        o.z = f2bf(a2 * inv); o.w = f2bf(a3 * inv);
        *(ushort4*)(abuf + (size_t)n * 256 + l32 * 4) = o;
    }
}

// wt[c][k] = bf16( k<128 ? w1_l[k][c] : w1_r[k-128][c] )   [512][256]
__global__ void cvt_w(const float* __restrict__ wl, const float* __restrict__ wr,
                      ushort* __restrict__ wt) {
    int i = blockIdx.x * blockDim.x + threadIdx.x;
    if (i >= 512 * 256) return;
    int k = i >> 9, c = i & 511;
    float v = (k < 128) ? wl[(size_t)k * 512 + c] : wr[(size_t)(k - 128) * 512 + c];
    wt[(size_t)c * 256 + k] = f2bf(v);
}

// wt2[c][k] = bf16( c<40 ? w2_l[k][c] : w2_r[k][c-40] )   [80][512]
__global__ void cvt_w2(const float* __restrict__ wl, const float* __restrict__ wr,
                       ushort* __restrict__ wt2) {
    int i = blockIdx.x * blockDim.x + threadIdx.x;
    if (i >= 80 * 512) return;
    int c = i >> 9, k = i & 511;
    float v = (c < 40) ? wl[(size_t)k * 40 + c] : wr[(size_t)k * 40 + (c - 40)];
    wt2[(size_t)c * 512 + k] = f2bf(v);
}

// h = relu(A @ WT^T + b)  A:[50000][256] bf16, WT:[512][256] bf16 -> h bf16
__global__ __launch_bounds__(256) void gemm1_mfma(
    const ushort* __restrict__ A, const ushort* __restrict__ BT,
    const float* __restrict__ bias, ushort* __restrict__ h) {
    __shared__ ushort As[128 * 64];
    __shared__ ushort Bs[128 * 64];
    int tid = threadIdx.x;
    int wave = tid >> 6, lane = tid & 63;
    int wm = wave >> 1, wn = wave & 1;
    int row0 = blockIdx.x * 128;
    int col0 = blockIdx.y * 128;
    f32x4 acc[4][4] = {};
    for (int kk = 0; kk < 256; kk += 64) {
        #pragma unroll
        for (int c = 0; c < 4; ++c) {
            int ch = wave + c * 4;
            int o = ch * 1024 + lane * 16;
            int row = o >> 7;
            int s = (o >> 4) & 7;
            int ssrc = s ^ (row & 7);
            int gr = row0 + row; if (gr > N_NODES - 1) gr = N_NODES - 1;
            gload_lds16(A + (size_t)gr * 256 + kk + (ssrc << 3), As + ch * 512);
            int gc = col0 + row;
            gload_lds16(BT + (size_t)gc * 256 + kk + (ssrc << 3), Bs + ch * 512);
        }
        __syncthreads();
        #pragma unroll
        for (int kc = 0; kc < 2; ++kc) {
            int sbase = kc * 4 + (lane >> 4);
            bf16x8 af[4], bfr[4];
            #pragma unroll
            for (int m = 0; m < 4; ++m) {
                int row = wm * 64 + m * 16 + (lane & 15);
                af[m] = *(const bf16x8*)(As + row * 64 + ((sbase ^ (row & 7)) << 3));
            }
            #pragma unroll
            for (int n = 0; n < 4; ++n) {
                int row = wn * 64 + n * 16 + (lane & 15);
                bfr[n] = *(const bf16x8*)(Bs + row * 64 + ((sbase ^ (row & 7)) << 3));
            }
            #pragma unroll
            for (int m = 0; m < 4; ++m)
                #pragma unroll
                for (int n = 0; n < 4; ++n)
                    acc[m][n] = __builtin_amdgcn_mfma_f32_16x16x32_bf16(af[m], bfr[n], acc[m][n], 0, 0, 0);
        }
        __syncthreads();
    }
    #pragma unroll
    for (int m = 0; m < 4; ++m) {
        #pragma unroll
        for (int j = 0; j < 4; ++j) {
            int grow = row0 + wm * 64 + m * 16 + (lane >> 4) * 4 + j;
            if (grow >= N_NODES) continue;
            #pragma unroll
            for (int n = 0; n < 4; ++n) {
                int gcol = col0 + wn * 64 + n * 16 + (lane & 15);
                float v = acc[m][n][j] + bias[gcol];
                h[(size_t)grow * 512 + gcol] = f2bf(v > 0.f ? v : 0.f);
            }
        }
    }
}

// [p|r] = h @ wt2^T   h:[50000][512] bf16, wt2:[80][512] bf16
__global__ __launch_bounds__(256) void gemm2_mfma(
    const ushort* __restrict__ hbf, const ushort* __restrict__ wt2,
    ushort* __restrict__ p, float* __restrict__ r) {
    __shared__ ushort As[128 * 64];
    __shared__ ushort Bs[80 * 64];
    int tid = threadIdx.x;
    int wave = tid >> 6, lane = tid & 63;
    int row0 = blockIdx.x * 128;
    f32x4 acc[2][5] = {};
    for (int kk = 0; kk < 512; kk += 64) {
        #pragma unroll
        for (int c = 0; c < 4; ++c) {
            int ch = wave + c * 4;
            int o = ch * 1024 + lane * 16;
            int row = o >> 7;
            int s = (o >> 4) & 7;
            int ssrc = s ^ (row & 7);
            int gr = row0 + row; if (gr > N_NODES - 1) gr = N_NODES - 1;
            gload_lds16(hbf + (size_t)gr * 512 + kk + (ssrc << 3), As + ch * 512);
        }
        for (int ch = wave; ch < 10; ch += 4) {
            int o = ch * 1024 + lane * 16;
            int row = o >> 7;
            int s = (o >> 4) & 7;
            int ssrc = s ^ (row & 7);
            gload_lds16(wt2 + (size_t)row * 512 + kk + (ssrc << 3), Bs + ch * 512);
        }
        __syncthreads();
        #pragma unroll
        for (int kc = 0; kc < 2; ++kc) {
            int sbase = kc * 4 + (lane >> 4);
            bf16x8 af[2], bfr[5];
            #pragma unroll
            for (int m = 0; m < 2; ++m) {
                int row = wave * 32 + m * 16 + (lane & 15);
                af[m] = *(const bf16x8*)(As + row * 64 + ((sbase ^ (row & 7)) << 3));
            }
            #pragma unroll
            for (int n = 0; n < 5; ++n) {
                int row = n * 16 + (lane & 15);
                bfr[n] = *(const bf16x8*)(Bs + row * 64 + ((sbase ^ (row & 7)) << 3));
            }
            #pragma unroll
            for (int m = 0; m < 2; ++m)
                #pragma unroll
                for (int n = 0; n < 5; ++n)
                    acc[m][n] = __builtin_amdgcn_mfma_f32_16x16x32_bf16(af[m], bfr[n], acc[m][n], 0, 0, 0);
        }
        __syncthreads();
    }
    #pragma unroll
    for (int m = 0; m < 2; ++m) {
        #pragma unroll
        for (int j = 0; j < 4; ++j) {
            int grow = row0 + wave * 32 + m * 16 + (lane >> 4) * 4 + j;
            if (grow >= N_NODES) continue;
            #pragma unroll
            for (int n = 0; n < 5; ++n) {
                int col = n * 16 + (lane & 15);
                float v = acc[m][n][j];
                if (col < 40) p[(size_t)grow * 40 + col] = f2bf(v);
                else          r[(size_t)grow * 40 + (col - 40)] = v;
            }
        }
    }
}

// out = log_softmax(mean_j p[src] + b2 + r)  one wave per node, lanes 0..39
__global__ void final_kernel(const ushort* __restrict__ p, const float* __restrict__ rr,
                             const float* __restrict__ b2,
                             const int* __restrict__ row_ptr, const int* __restrict__ csr_src,
                             float* __restrict__ out) {
    int wid = threadIdx.x >> 6;
    int lane = threadIdx.x & 63;
    int n = blockIdx.x * 4 + wid;
    if (n >= N_NODES) return;
    int beg = row_ptr[n], end = row_ptr[n + 1];
    float acc0 = 0.f, acc1 = 0.f, acc2 = 0.f, acc3 = 0.f;
    int e = beg;
    if (lane < OUT_DIM) {
        for (; e + 3 < end; e += 4) {
            int s0 = csr_src[e], s1 = csr_src[e + 1];
            int s2 = csr_src[e + 2], s3 = csr_src[e + 3];
            acc0 += bf2f(p[(size_t)s0 * OUT_DIM + lane]);
            acc1 += bf2f(p[(size_t)s1 * OUT_DIM + lane]);
            acc2 += bf2f(p[(size_t)s2 * OUT_DIM + lane]);
            acc3 += bf2f(p[(size_t)s3 * OUT_DIM + lane]);
        }
        for (; e < end; ++e)
            acc0 += bf2f(p[(size_t)csr_src[e] * OUT_DIM + lane]);
    }
    int d = end - beg; if (d < 1) d = 1;
    float inv = 1.0f / (float)d;
    float v = (lane < OUT_DIM)
                  ? ((acc0 + acc1 + acc2 + acc3) * inv + b2[lane] + rr[(size_t)n * OUT_DIM + lane])
                  : -INFINITY;
    float m = v;
    #pragma unroll
    for (int off = 32; off; off >>= 1) m = fmaxf(m, __shfl_xor(m, off));
    float ex = (lane < OUT_DIM) ? expf(v - m) : 0.f;
    float ssum = ex;
    #pragma unroll
    for (int off = 32; off; off >>= 1) ssum += __shfl_xor(ssum, off);
    if (lane < OUT_DIM) out[(size_t)n * OUT_DIM + lane] = (v - m) - logf(ssum);
}

extern "C" void kernel_launch(void* const* d_in, const int* in_sizes, int n_in,
                              void* d_out, int out_size, void* d_ws, size_t ws_size,
                              hipStream_t stream) {
    const float* x    = (const float*)d_in[0];
    const int*   edge = (const int*)d_in[1];
    const int*   srce = edge;
    const int*   dste = edge + N_EDGES;
    const float* w1l  = (const float*)d_in[2];
    const float* b1   = (const float*)d_in[3];
    const float* w1r  = (const float*)d_in[4];
    const float* w2l  = (const float*)d_in[5];
    const float* b2   = (const float*)d_in[6];
    const float* w2r  = (const float*)d_in[7];
    float* out = (float*)d_out;

    char* ws = (char*)d_ws;
    size_t off = 0;
    auto alloc = [&](size_t bytes) -> void* {
        void* ptr = ws + off;
        off = (off + bytes + 255) & ~(size_t)255;
        return ptr;
    };
    int* deg     = (int*)alloc((size_t)2 * N_NODES * 4);
    int* cursor  = deg + N_NODES;
    int* row_ptr = (int*)alloc((size_t)(N_NODES + 1) * 4);
    int* bsum    = (int*)alloc((size_t)NB_SCAN * 4);
    int* csr_src = (int*)alloc((size_t)N_EDGES * 4);
    ushort* abuf = (ushort*)alloc((size_t)N_NODES * 256 * 2);   // [agg|x] bf16
    ushort* wt   = (ushort*)alloc((size_t)512 * 256 * 2);       // [w1_l;w1_r]^T bf16
    ushort* wt2  = (ushort*)alloc((size_t)80 * 512 * 2);        // [w2_l|w2_r]^T bf16
    ushort* h    = (ushort*)alloc((size_t)N_NODES * HID * 2);   // h bf16
    ushort* p    = (ushort*)alloc((size_t)N_NODES * OUT_DIM * 2);  // p bf16
    float* rbuf  = (float*)alloc((size_t)N_NODES * OUT_DIM * 4);

    zero_ints<<<(2 * N_NODES + 255) / 256, 256, 0, stream>>>(deg, 2 * N_NODES);
    count_deg_part<<<NRANGE * NCHUNK, 256, 0, stream>>>(dste, deg);
    deg_block_sums<<<NB_SCAN, 256, 0, stream>>>(deg, bsum);
    scan_bsum<<<1, 256, 0, stream>>>(bsum);
    scan_fill<<<NB_SCAN, 256, 0, stream>>>(deg, bsum, row_ptr);
    fill_csr_part<<<NRANGE * NCHUNK, 256, 0, stream>>>(srce, dste, row_ptr, cursor, csr_src);
    cvt_x<<<(N_NODES * 32 + 255) / 256, 256, 0, stream>>>(x, abuf);
    cvt_w<<<(512 * 256 + 255) / 256, 256, 0, stream>>>(w1l, w1r, wt);
    cvt_w2<<<(80 * 512 + 255) / 256, 256, 0, stream>>>(w2l, w2r, wt2);
    agg_x<<<(N_NODES + 3) / 4, 256, 0, stream>>>(row_ptr, csr_src, abuf);
    gemm1_mfma<<<dim3((N_NODES + 127) / 128, 4), 256, 0, stream>>>(abuf, wt, b1, h);
    gemm2_mfma<<<(N_NODES + 127) / 128, 256, 0, stream>>>(h, wt2, p, rbuf);
    final_kernel<<<(N_NODES + 3) / 4, 256, 0, stream>>>(p, rbuf, b2, row_ptr, csr_src, out);
}

// Round 8
// 222.679 us; speedup vs baseline: 3.0915x; 1.0081x over previous
//
#include <hip/hip_runtime.h>
#include <math.h>

#define N_NODES 50000
#define N_EDGES 800000
#define IN_DIM 128
#define HID 512
#define OUT_DIM 40
#define NB_SCAN ((N_NODES + 255) / 256)   // 196
#define NRANGE 8
#define RANGE_SZ ((N_NODES + NRANGE - 1) / NRANGE)   // 6250
#define NCHUNK 250
#define PER_CHUNK 3200   // NCHUNK*PER_CHUNK == N_EDGES, %4 == 0

typedef __attribute__((ext_vector_type(8))) short bf16x8;
typedef __attribute__((ext_vector_type(4))) float f32x4;

__device__ __forceinline__ ushort f2bf(float f) {
    unsigned u = __float_as_uint(f);
    u += 0x7fff + ((u >> 16) & 1);   // round-to-nearest-even
    return (ushort)(u >> 16);
}

__device__ __forceinline__ float bf2f(ushort u) {
    return __uint_as_float(((unsigned)u) << 16);
}

// async global->LDS, 16B per lane, dest = wave-uniform base + lane*16
__device__ __forceinline__ void gload_lds16(const ushort* g, ushort* l) {
    __builtin_amdgcn_global_load_lds(
        (__attribute__((address_space(1))) void*)g,
        (__attribute__((address_space(3))) void*)l, 16, 0, 0);
}

__global__ void zero_ints(int* __restrict__ a, int n) {
    int i = blockIdx.x * blockDim.x + threadIdx.x;
    if (i < n) a[i] = 0;
}

// XCD-range-partitioned histogram, 2000 blocks (8 ranges x 250 chunks),
// int4 edge loads -> 4 independent atomic chains per lane
__global__ void count_deg_part(const int* __restrict__ dst, int* __restrict__ deg) {
    int range = blockIdx.x & (NRANGE - 1);
    int chunk = blockIdx.x >> 3;
    int lo = range * RANGE_SZ;
    int hi = lo + RANGE_SZ; if (hi > N_NODES) hi = N_NODES;
    int beg = chunk * PER_CHUNK;
    for (int e = beg + threadIdx.x * 4; e < beg + PER_CHUNK; e += 1024) {
        int4 d4 = *(const int4*)(dst + e);
        if (d4.x >= lo && d4.x < hi) atomicAdd(&deg[d4.x], 1);
        if (d4.y >= lo && d4.y < hi) atomicAdd(&deg[d4.y], 1);
        if (d4.z >= lo && d4.z < hi) atomicAdd(&deg[d4.z], 1);
        if (d4.w >= lo && d4.w < hi) atomicAdd(&deg[d4.w], 1);
    }
}

// --- 3-stage parallel exclusive scan: deg[50000] -> row_ptr[50001] ---
__global__ void deg_block_sums(const int* __restrict__ deg, int* __restrict__ bsum) {
    __shared__ int red[256];
    int tid = threadIdx.x;
    int i = blockIdx.x * 256 + tid;
    red[tid] = (i < N_NODES) ? deg[i] : 0;
    __syncthreads();
    #pragma unroll
    for (int off = 128; off; off >>= 1) {
        if (tid < off) red[tid] += red[tid + off];
        __syncthreads();
    }
    if (tid == 0) bsum[blockIdx.x] = red[0];
}

__global__ void scan_bsum(int* __restrict__ bsum) {
    __shared__ int s[256];
    int tid = threadIdx.x;
    int v = (tid < NB_SCAN) ? bsum[tid] : 0;
    s[tid] = v;
    __syncthreads();
    #pragma unroll
    for (int off = 1; off < 256; off <<= 1) {
        int add = (tid >= off) ? s[tid - off] : 0;
        __syncthreads();
        s[tid] += add;
        __syncthreads();
    }
    if (tid < NB_SCAN) bsum[tid] = s[tid] - v;   // exclusive
}

__global__ void scan_fill(const int* __restrict__ deg, const int* __restrict__ bsum,
                          int* __restrict__ row_ptr) {
    __shared__ int s[256];
    int tid = threadIdx.x;
    int i = blockIdx.x * 256 + tid;
    int v = (i < N_NODES) ? deg[i] : 0;
    s[tid] = v;
    __syncthreads();
    #pragma unroll
    for (int off = 1; off < 256; off <<= 1) {
        int add = (tid >= off) ? s[tid - off] : 0;
        __syncthreads();
        s[tid] += add;
        __syncthreads();
    }
    int excl = s[tid] - v + bsum[blockIdx.x];
    if (i < N_NODES) row_ptr[i] = excl;
    if (i == N_NODES - 1) row_ptr[N_NODES] = excl + v;
}

// XCD-range-partitioned CSR fill, 2000 blocks, int4 loads of src+dst
__global__ void fill_csr_part(const int* __restrict__ src, const int* __restrict__ dst,
                              const int* __restrict__ row_ptr, int* __restrict__ cursor,
                              int* __restrict__ csr_src) {
    int range = blockIdx.x & (NRANGE - 1);
    int chunk = blockIdx.x >> 3;
    int lo = range * RANGE_SZ;
    int hi = lo + RANGE_SZ; if (hi > N_NODES) hi = N_NODES;
    int beg = chunk * PER_CHUNK;
    for (int e = beg + threadIdx.x * 4; e < beg + PER_CHUNK; e += 1024) {
        int4 d4 = *(const int4*)(dst + e);
        int4 s4 = *(const int4*)(src + e);
        if (d4.x >= lo && d4.x < hi) {
            int pos = atomicAdd(&cursor[d4.x], 1);
            csr_src[row_ptr[d4.x] + pos] = s4.x;
        }
        if (d4.y >= lo && d4.y < hi) {
            int pos = atomicAdd(&cursor[d4.y], 1);
            csr_src[row_ptr[d4.y] + pos] = s4.y;
        }
        if (d4.z >= lo && d4.z < hi) {
            int pos = atomicAdd(&cursor[d4.z], 1);
            csr_src[row_ptr[d4.z] + pos] = s4.z;
        }
        if (d4.w >= lo && d4.w < hi) {
            int pos = atomicAdd(&cursor[d4.w], 1);
            csr_src[row_ptr[d4.w] + pos] = s4.w;
        }
    }
}

// abuf[n][128..255] = bf16(x[n][:])  (must run BEFORE agg_x: agg gathers from it)
__global__ void cvt_x(const float* __restrict__ x, ushort* __restrict__ abuf) {
    int i = blockIdx.x * blockDim.x + threadIdx.x;
    if (i >= N_NODES * 32) return;
    int n = i >> 5, q = i & 31;
    float4 v = *(const float4*)(x + (size_t)n * 128 + q * 4);
    ushort4 o;
    o.x = f2bf(v.x); o.y = f2bf(v.y); o.z = f2bf(v.z); o.w = f2bf(v.w);
    *(ushort4*)(abuf + (size_t)n * 256 + 128 + q * 4) = o;
}

// one wave per node: mean of bf16-x[src] rows (from abuf x-half, 256B/row)
__global__ void agg_x(const int* __restrict__ row_ptr,
                      const int* __restrict__ csr_src, ushort* __restrict__ abuf) {
    int wid = threadIdx.x >> 6;
    int lane = threadIdx.x & 63;
    int n = blockIdx.x * 4 + wid;
    if (n >= N_NODES) return;
    int beg = row_ptr[n], end = row_ptr[n + 1];
    int half = lane >> 5, l32 = lane & 31;
    const ushort* xb = abuf + 128;   // x-half of each 256-elem row
    float a0 = 0, a1 = 0, a2 = 0, a3 = 0;
    float b0 = 0, b1 = 0, b2_ = 0, b3 = 0;
    int e = beg + half;
    for (; e + 2 < end; e += 4) {
        int s0 = csr_src[e], s1 = csr_src[e + 2];
        ushort4 v0 = *(const ushort4*)(xb + (size_t)s0 * 256 + l32 * 4);
        ushort4 v1 = *(const ushort4*)(xb + (size_t)s1 * 256 + l32 * 4);
        a0 += bf2f(v0.x); a1 += bf2f(v0.y); a2 += bf2f(v0.z); a3 += bf2f(v0.w);
        b0 += bf2f(v1.x); b1 += bf2f(v1.y); b2_ += bf2f(v1.z); b3 += bf2f(v1.w);
    }
    if (e < end) {
        int s = csr_src[e];
        ushort4 v = *(const ushort4*)(xb + (size_t)s * 256 + l32 * 4);
        a0 += bf2f(v.x); a1 += bf2f(v.y); a2 += bf2f(v.z); a3 += bf2f(v.w);
    }
    a0 += b0; a1 += b1; a2 += b2_; a3 += b3;
    a0 += __shfl_xor(a0, 32);
    a1 += __shfl_xor(a1, 32);
    a2 += __shfl_xor(a2, 32);
    a3 += __shfl_xor(a3, 32);
    int d = end - beg; if (d < 1) d = 1;
    float inv = 1.0f / (float)d;
    if (half == 0) {
        ushort4 o;
        o.x = f2bf(a0 * inv); o.y = f2bf(a1 * inv);
        o.z = f2bf(a2 * inv); o.w = f2bf(a3 * inv);
        *(ushort4*)(abuf + (size_t)n * 256 + l32 * 4) = o;
    }
}

// wt[c][k] = bf16( k<128 ? w1_l[k][c] : w1_r[k-128][c] )   [512][256]
__global__ void cvt_w(const float* __restrict__ wl, const float* __restrict__ wr,
                      ushort* __restrict__ wt) {
    int i = blockIdx.x * blockDim.x + threadIdx.x;
    if (i >= 512 * 256) return;
    int k = i >> 9, c = i & 511;
    float v = (k < 128) ? wl[(size_t)k * 512 + c] : wr[(size_t)(k - 128) * 512 + c];
    wt[(size_t)c * 256 + k] = f2bf(v);
}

// wt2[c][k] = bf16( c<40 ? w2_l[k][c] : w2_r[k][c-40] )   [80][512]
__global__ void cvt_w2(const float* __restrict__ wl, const float* __restrict__ wr,
                       ushort* __restrict__ wt2) {
    int i = blockIdx.x * blockDim.x + threadIdx.x;
    if (i >= 80 * 512) return;
    int c = i >> 9, k = i & 511;
    float v = (c < 40) ? wl[(size_t)k * 40 + c] : wr[(size_t)k * 40 + (c - 40)];
    wt2[(size_t)c * 512 + k] = f2bf(v);
}

// h = relu(A @ WT^T + b)  A:[50000][256] bf16, WT:[512][256] bf16 -> h bf16
__global__ __launch_bounds__(256) void gemm1_mfma(
    const ushort* __restrict__ A, const ushort* __restrict__ BT,
    const float* __restrict__ bias, ushort* __restrict__ h) {
    __shared__ ushort As[128 * 64];
    __shared__ ushort Bs[128 * 64];
    int tid = threadIdx.x;
    int wave = tid >> 6, lane = tid & 63;
    int wm = wave >> 1, wn = wave & 1;
    int row0 = blockIdx.x * 128;
    int col0 = blockIdx.y * 128;
    f32x4 acc[4][4] = {};
    for (int kk = 0; kk < 256; kk += 64) {
        #pragma unroll
        for (int c = 0; c < 4; ++c) {
            int ch = wave + c * 4;
            int o = ch * 1024 + lane * 16;
            int row = o >> 7;
            int s = (o >> 4) & 7;
            int ssrc = s ^ (row & 7);
            int gr = row0 + row; if (gr > N_NODES - 1) gr = N_NODES - 1;
            gload_lds16(A + (size_t)gr * 256 + kk + (ssrc << 3), As + ch * 512);
            int gc = col0 + row;
            gload_lds16(BT + (size_t)gc * 256 + kk + (ssrc << 3), Bs + ch * 512);
        }
        __syncthreads();
        #pragma unroll
        for (int kc = 0; kc < 2; ++kc) {
            int sbase = kc * 4 + (lane >> 4);
            bf16x8 af[4], bfr[4];
            #pragma unroll
            for (int m = 0; m < 4; ++m) {
                int row = wm * 64 + m * 16 + (lane & 15);
                af[m] = *(const bf16x8*)(As + row * 64 + ((sbase ^ (row & 7)) << 3));
            }
            #pragma unroll
            for (int n = 0; n < 4; ++n) {
                int row = wn * 64 + n * 16 + (lane & 15);
                bfr[n] = *(const bf16x8*)(Bs + row * 64 + ((sbase ^ (row & 7)) << 3));
            }
            #pragma unroll
            for (int m = 0; m < 4; ++m)
                #pragma unroll
                for (int n = 0; n < 4; ++n)
                    acc[m][n] = __builtin_amdgcn_mfma_f32_16x16x32_bf16(af[m], bfr[n], acc[m][n], 0, 0, 0);
        }
        __syncthreads();
    }
    #pragma unroll
    for (int m = 0; m < 4; ++m) {
        #pragma unroll
        for (int j = 0; j < 4; ++j) {
            int grow = row0 + wm * 64 + m * 16 + (lane >> 4) * 4 + j;
            if (grow >= N_NODES) continue;
            #pragma unroll
            for (int n = 0; n < 4; ++n) {
                int gcol = col0 + wn * 64 + n * 16 + (lane & 15);
                float v = acc[m][n][j] + bias[gcol];
                h[(size_t)grow * 512 + gcol] = f2bf(v > 0.f ? v : 0.f);
            }
        }
    }
}

// [p|r] = h @ wt2^T   h:[50000][512] bf16, wt2:[80][512] bf16
__global__ __launch_bounds__(256) void gemm2_mfma(
    const ushort* __restrict__ hbf, const ushort* __restrict__ wt2,
    ushort* __restrict__ p, float* __restrict__ r) {
    __shared__ ushort As[128 * 64];
    __shared__ ushort Bs[80 * 64];
    int tid = threadIdx.x;
    int wave = tid >> 6, lane = tid & 63;
    int row0 = blockIdx.x * 128;
    f32x4 acc[2][5] = {};
    for (int kk = 0; kk < 512; kk += 64) {
        #pragma unroll
        for (int c = 0; c < 4; ++c) {
            int ch = wave + c * 4;
            int o = ch * 1024 + lane * 16;
            int row = o >> 7;
            int s = (o >> 4) & 7;
            int ssrc = s ^ (row & 7);
            int gr = row0 + row; if (gr > N_NODES - 1) gr = N_NODES - 1;
            gload_lds16(hbf + (size_t)gr * 512 + kk + (ssrc << 3), As + ch * 512);
        }
        for (int ch = wave; ch < 10; ch += 4) {
            int o = ch * 1024 + lane * 16;
            int row = o >> 7;
            int s = (o >> 4) & 7;
            int ssrc = s ^ (row & 7);
            gload_lds16(wt2 + (size_t)row * 512 + kk + (ssrc << 3), Bs + ch * 512);
        }
        __syncthreads();
        #pragma unroll
        for (int kc = 0; kc < 2; ++kc) {
            int sbase = kc * 4 + (lane >> 4);
            bf16x8 af[2], bfr[5];
            #pragma unroll
            for (int m = 0; m < 2; ++m) {
                int row = wave * 32 + m * 16 + (lane & 15);
                af[m] = *(const bf16x8*)(As + row * 64 + ((sbase ^ (row & 7)) << 3));
            }
            #pragma unroll
            for (int n = 0; n < 5; ++n) {
                int row = n * 16 + (lane & 15);
                bfr[n] = *(const bf16x8*)(Bs + row * 64 + ((sbase ^ (row & 7)) << 3));
            }
            #pragma unroll
            for (int m = 0; m < 2; ++m)
                #pragma unroll
                for (int n = 0; n < 5; ++n)
                    acc[m][n] = __builtin_amdgcn_mfma_f32_16x16x32_bf16(af[m], bfr[n], acc[m][n], 0, 0, 0);
        }
        __syncthreads();
    }
    #pragma unroll
    for (int m = 0; m < 2; ++m) {
        #pragma unroll
        for (int j = 0; j < 4; ++j) {
            int grow = row0 + wave * 32 + m * 16 + (lane >> 4) * 4 + j;
            if (grow >= N_NODES) continue;
            #pragma unroll
            for (int n = 0; n < 5; ++n) {
                int col = n * 16 + (lane & 15);
                float v = acc[m][n][j];
                if (col < 40) p[(size_t)grow * 40 + col] = f2bf(v);
                else          r[(size_t)grow * 40 + (col - 40)] = v;
            }
        }
    }
}

// out = log_softmax(mean_j p[src] + b2 + r)  one wave per node, lanes 0..39
__global__ void final_kernel(const ushort* __restrict__ p, const float* __restrict__ rr,
                             const float* __restrict__ b2,
                             const int* __restrict__ row_ptr, const int* __restrict__ csr_src,
                             float* __restrict__ out) {
    int wid = threadIdx.x >> 6;
    int lane = threadIdx.x & 63;
    int n = blockIdx.x * 4 + wid;
    if (n >= N_NODES) return;
    int beg = row_ptr[n], end = row_ptr[n + 1];
    float acc0 = 0.f, acc1 = 0.f, acc2 = 0.f, acc3 = 0.f;
    int e = beg;
    if (lane < OUT_DIM) {
        for (; e + 3 < end; e += 4) {
            int s0 = csr_src[e], s1 = csr_src[e + 1];
            int s2 = csr_src[e + 2], s3 = csr_src[e + 3];
            acc0 += bf2f(p[(size_t)s0 * OUT_DIM + lane]);
            acc1 += bf2f(p[(size_t)s1 * OUT_DIM + lane]);
            acc2 += bf2f(p[(size_t)s2 * OUT_DIM + lane]);
            acc3 += bf2f(p[(size_t)s3 * OUT_DIM + lane]);
        }
        for (; e < end; ++e)
            acc0 += bf2f(p[(size_t)csr_src[e] * OUT_DIM + lane]);
    }
    int d = end - beg; if (d < 1) d = 1;
    float inv = 1.0f / (float)d;
    float v = (lane < OUT_DIM)
                  ? ((acc0 + acc1 + acc2 + acc3) * inv + b2[lane] + rr[(size_t)n * OUT_DIM + lane])
                  : -INFINITY;
    float m = v;
    #pragma unroll
    for (int off = 32; off; off >>= 1) m = fmaxf(m, __shfl_xor(m, off));
    float ex = (lane < OUT_DIM) ? expf(v - m) : 0.f;
    float ssum = ex;
    #pragma unroll
    for (int off = 32; off; off >>= 1) ssum += __shfl_xor(ssum, off);
    if (lane < OUT_DIM) out[(size_t)n * OUT_DIM + lane] = (v - m) - logf(ssum);
}

extern "C" void kernel_launch(void* const* d_in, const int* in_sizes, int n_in,
                              void* d_out, int out_size, void* d_ws, size_t ws_size,
                              hipStream_t stream) {
    const float* x    = (const float*)d_in[0];
    const int*   edge = (const int*)d_in[1];
    const int*   srce = edge;
    const int*   dste = edge + N_EDGES;
    const float* w1l  = (const float*)d_in[2];
    const float* b1   = (const float*)d_in[3];
    const float* w1r  = (const float*)d_in[4];
    const float* w2l  = (const float*)d_in[5];
    const float* b2   = (const float*)d_in[6];
    const float* w2r  = (const float*)d_in[7];
    float* out = (float*)d_out;

    char* ws = (char*)d_ws;
    size_t off = 0;
    auto alloc = [&](size_t bytes) -> void* {
        void* ptr = ws + off;
        off = (off + bytes + 255) & ~(size_t)255;
        return ptr;
    };
    int* deg     = (int*)alloc((size_t)2 * N_NODES * 4);
    int* cursor  = deg + N_NODES;
    int* row_ptr = (int*)alloc((size_t)(N_NODES + 1) * 4);
    int* bsum    = (int*)alloc((size_t)NB_SCAN * 4);
    int* csr_src = (int*)alloc((size_t)N_EDGES * 4);
    ushort* abuf = (ushort*)alloc((size_t)N_NODES * 256 * 2);   // [agg|x] bf16
    ushort* wt   = (ushort*)alloc((size_t)512 * 256 * 2);       // [w1_l;w1_r]^T bf16
    ushort* wt2  = (ushort*)alloc((size_t)80 * 512 * 2);        // [w2_l|w2_r]^T bf16
    ushort* h    = (ushort*)alloc((size_t)N_NODES * HID * 2);   // h bf16
    ushort* p    = (ushort*)alloc((size_t)N_NODES * OUT_DIM * 2);  // p bf16
    float* rbuf  = (float*)alloc((size_t)N_NODES * OUT_DIM * 4);

    zero_ints<<<(2 * N_NODES + 255) / 256, 256, 0, stream>>>(deg, 2 * N_NODES);
    count_deg_part<<<NRANGE * NCHUNK, 256, 0, stream>>>(dste, deg);
    deg_block_sums<<<NB_SCAN, 256, 0, stream>>>(deg, bsum);
    scan_bsum<<<1, 256, 0, stream>>>(bsum);
    scan_fill<<<NB_SCAN, 256, 0, stream>>>(deg, bsum, row_ptr);
    fill_csr_part<<<NRANGE * NCHUNK, 256, 0, stream>>>(srce, dste, row_ptr, cursor, csr_src);
    cvt_x<<<(N_NODES * 32 + 255) / 256, 256, 0, stream>>>(x, abuf);
    cvt_w<<<(512 * 256 + 255) / 256, 256, 0, stream>>>(w1l, w1r, wt);
    cvt_w2<<<(80 * 512 + 255) / 256, 256, 0, stream>>>(w2l, w2r, wt2);
    agg_x<<<(N_NODES + 3) / 4, 256, 0, stream>>>(row_ptr, csr_src, abuf);
    gemm1_mfma<<<dim3((N_NODES + 127) / 128, 4), 256, 0, stream>>>(abuf, wt, b1, h);
    gemm2_mfma<<<(N_NODES + 127) / 128, 256, 0, stream>>>(h, wt2, p, rbuf);
    final_kernel<<<(N_NODES + 3) / 4, 256, 0, stream>>>(p, rbuf, b2, row_ptr, csr_src, out);
}

// Round 9
// 222.665 us; speedup vs baseline: 3.0917x; 1.0001x over previous
//
#include <hip/hip_runtime.h>
#include <math.h>

#define N_NODES 50000
#define N_EDGES 800000
#define IN_DIM 128
#define HID 512
#define OUT_DIM 40
#define NB_SCAN ((N_NODES + 255) / 256)   // 196
#define NRANGE 8
#define RANGE_SZ ((N_NODES + NRANGE - 1) / NRANGE)   // 6250
#define NCHUNK 250
#define PER_CHUNK 3200   // NCHUNK*PER_CHUNK == N_EDGES, %4 == 0

typedef __attribute__((ext_vector_type(8))) short bf16x8;
typedef __attribute__((ext_vector_type(4))) float f32x4;

__device__ __forceinline__ ushort f2bf(float f) {
    unsigned u = __float_as_uint(f);
    u += 0x7fff + ((u >> 16) & 1);   // round-to-nearest-even
    return (ushort)(u >> 16);
}

__device__ __forceinline__ float bf2f(ushort u) {
    return __uint_as_float(((unsigned)u) << 16);
}

// async global->LDS, 16B per lane, dest = wave-uniform base + lane*16
__device__ __forceinline__ void gload_lds16(const ushort* g, ushort* l) {
    __builtin_amdgcn_global_load_lds(
        (__attribute__((address_space(1))) void*)g,
        (__attribute__((address_space(3))) void*)l, 16, 0, 0);
}

__global__ void zero_ints(int* __restrict__ a, int n) {
    int i = blockIdx.x * blockDim.x + threadIdx.x;
    if (i < n) a[i] = 0;
}

// XCD-range-partitioned histogram, 2000 blocks (8 ranges x 250 chunks)
__global__ void count_deg_part(const int* __restrict__ dst, int* __restrict__ deg) {
    int range = blockIdx.x & (NRANGE - 1);
    int chunk = blockIdx.x >> 3;
    int lo = range * RANGE_SZ;
    int hi = lo + RANGE_SZ; if (hi > N_NODES) hi = N_NODES;
    int beg = chunk * PER_CHUNK;
    for (int e = beg + threadIdx.x * 4; e < beg + PER_CHUNK; e += 1024) {
        int4 d4 = *(const int4*)(dst + e);
        if (d4.x >= lo && d4.x < hi) atomicAdd(&deg[d4.x], 1);
        if (d4.y >= lo && d4.y < hi) atomicAdd(&deg[d4.y], 1);
        if (d4.z >= lo && d4.z < hi) atomicAdd(&deg[d4.z], 1);
        if (d4.w >= lo && d4.w < hi) atomicAdd(&deg[d4.w], 1);
    }
}

// --- 3-stage parallel exclusive scan: deg[50000] -> row_ptr[50001] ---
__global__ void deg_block_sums(const int* __restrict__ deg, int* __restrict__ bsum) {
    __shared__ int red[256];
    int tid = threadIdx.x;
    int i = blockIdx.x * 256 + tid;
    red[tid] = (i < N_NODES) ? deg[i] : 0;
    __syncthreads();
    #pragma unroll
    for (int off = 128; off; off >>= 1) {
        if (tid < off) red[tid] += red[tid + off];
        __syncthreads();
    }
    if (tid == 0) bsum[blockIdx.x] = red[0];
}

__global__ void scan_bsum(int* __restrict__ bsum) {
    __shared__ int s[256];
    int tid = threadIdx.x;
    int v = (tid < NB_SCAN) ? bsum[tid] : 0;
    s[tid] = v;
    __syncthreads();
    #pragma unroll
    for (int off = 1; off < 256; off <<= 1) {
        int add = (tid >= off) ? s[tid - off] : 0;
        __syncthreads();
        s[tid] += add;
        __syncthreads();
    }
    if (tid < NB_SCAN) bsum[tid] = s[tid] - v;   // exclusive
}

__global__ void scan_fill(const int* __restrict__ deg, const int* __restrict__ bsum,
                          int* __restrict__ row_ptr) {
    __shared__ int s[256];
    int tid = threadIdx.x;
    int i = blockIdx.x * 256 + tid;
    int v = (i < N_NODES) ? deg[i] : 0;
    s[tid] = v;
    __syncthreads();
    #pragma unroll
    for (int off = 1; off < 256; off <<= 1) {
        int add = (tid >= off) ? s[tid - off] : 0;
        __syncthreads();
        s[tid] += add;
        __syncthreads();
    }
    int excl = s[tid] - v + bsum[blockIdx.x];
    if (i < N_NODES) row_ptr[i] = excl;
    if (i == N_NODES - 1) row_ptr[N_NODES] = excl + v;
}

// XCD-range-partitioned CSR fill, 2000 blocks, int4 loads of src+dst
__global__ void fill_csr_part(const int* __restrict__ src, const int* __restrict__ dst,
                              const int* __restrict__ row_ptr, int* __restrict__ cursor,
                              int* __restrict__ csr_src) {
    int range = blockIdx.x & (NRANGE - 1);
    int chunk = blockIdx.x >> 3;
    int lo = range * RANGE_SZ;
    int hi = lo + RANGE_SZ; if (hi > N_NODES) hi = N_NODES;
    int beg = chunk * PER_CHUNK;
    for (int e = beg + threadIdx.x * 4; e < beg + PER_CHUNK; e += 1024) {
        int4 d4 = *(const int4*)(dst + e);
        int4 s4 = *(const int4*)(src + e);
        if (d4.x >= lo && d4.x < hi) {
            int pos = atomicAdd(&cursor[d4.x], 1);
            csr_src[row_ptr[d4.x] + pos] = s4.x;
        }
        if (d4.y >= lo && d4.y < hi) {
            int pos = atomicAdd(&cursor[d4.y], 1);
            csr_src[row_ptr[d4.y] + pos] = s4.y;
        }
        if (d4.z >= lo && d4.z < hi) {
            int pos = atomicAdd(&cursor[d4.z], 1);
            csr_src[row_ptr[d4.z] + pos] = s4.z;
        }
        if (d4.w >= lo && d4.w < hi) {
            int pos = atomicAdd(&cursor[d4.w], 1);
            csr_src[row_ptr[d4.w] + pos] = s4.w;
        }
    }
}

// abuf[n][128..255] = bf16(x[n][:])  (must run BEFORE agg_x)
__global__ void cvt_x(const float* __restrict__ x, ushort* __restrict__ abuf) {
    int i = blockIdx.x * blockDim.x + threadIdx.x;
    if (i >= N_NODES * 32) return;
    int n = i >> 5, q = i & 31;
    float4 v = *(const float4*)(x + (size_t)n * 128 + q * 4);
    ushort4 o;
    o.x = f2bf(v.x); o.y = f2bf(v.y); o.z = f2bf(v.z); o.w = f2bf(v.w);
    *(ushort4*)(abuf + (size_t)n * 256 + 128 + q * 4) = o;
}

// one wave per node: mean of bf16-x[src] rows (from abuf x-half, 256B/row)
__global__ void agg_x(const int* __restrict__ row_ptr,
                      const int* __restrict__ csr_src, ushort* __restrict__ abuf) {
    int wid = threadIdx.x >> 6;
    int lane = threadIdx.x & 63;
    int n = blockIdx.x * 4 + wid;
    if (n >= N_NODES) return;
    int beg = row_ptr[n], end = row_ptr[n + 1];
    int half = lane >> 5, l32 = lane & 31;
    const ushort* xb = abuf + 128;   // x-half of each 256-elem row
    float a0 = 0, a1 = 0, a2 = 0, a3 = 0;
    float b0 = 0, b1 = 0, b2_ = 0, b3 = 0;
    int e = beg + half;
    for (; e + 2 < end; e += 4) {
        int s0 = csr_src[e], s1 = csr_src[e + 2];
        ushort4 v0 = *(const ushort4*)(xb + (size_t)s0 * 256 + l32 * 4);
        ushort4 v1 = *(const ushort4*)(xb + (size_t)s1 * 256 + l32 * 4);
        a0 += bf2f(v0.x); a1 += bf2f(v0.y); a2 += bf2f(v0.z); a3 += bf2f(v0.w);
        b0 += bf2f(v1.x); b1 += bf2f(v1.y); b2_ += bf2f(v1.z); b3 += bf2f(v1.w);
    }
    if (e < end) {
        int s = csr_src[e];
        ushort4 v = *(const ushort4*)(xb + (size_t)s * 256 + l32 * 4);
        a0 += bf2f(v.x); a1 += bf2f(v.y); a2 += bf2f(v.z); a3 += bf2f(v.w);
    }
    a0 += b0; a1 += b1; a2 += b2_; a3 += b3;
    a0 += __shfl_xor(a0, 32);
    a1 += __shfl_xor(a1, 32);
    a2 += __shfl_xor(a2, 32);
    a3 += __shfl_xor(a3, 32);
    int d = end - beg; if (d < 1) d = 1;
    float inv = 1.0f / (float)d;
    if (half == 0) {
        ushort4 o;
        o.x = f2bf(a0 * inv); o.y = f2bf(a1 * inv);
        o.z = f2bf(a2 * inv); o.w = f2bf(a3 * inv);
        *(ushort4*)(abuf + (size_t)n * 256 + l32 * 4) = o;
    }
}

// merged weight transpose+convert: wt[512][256] and wt2[80][512]
__global__ void cvt_weights(const float* __restrict__ w1l, const float* __restrict__ w1r,
                            const float* __restrict__ w2l, const float* __restrict__ w2r,
                            ushort* __restrict__ wt, ushort* __restrict__ wt2) {
    int i = blockIdx.x * blockDim.x + threadIdx.x;
    if (i < 512 * 256) {
        int k = i >> 9, c = i & 511;
        float v = (k < 128) ? w1l[(size_t)k * 512 + c] : w1r[(size_t)(k - 128) * 512 + c];
        wt[(size_t)c * 256 + k] = f2bf(v);
    } else if (i < 512 * 256 + 80 * 512) {
        int j = i - 512 * 256;
        int c = j >> 9, k = j & 511;
        float v = (c < 40) ? w2l[(size_t)k * 40 + c] : w2r[(size_t)k * 40 + (c - 40)];
        wt2[(size_t)c * 512 + k] = f2bf(v);
    }
}

// h = relu(A @ WT^T + b)  A:[50000][256] bf16, WT:[512][256] bf16 -> h bf16
// 2-phase dbuf pipeline + bijective XCD swizzle (y-fastest: A-panel stays on one XCD)
__global__ __launch_bounds__(256) void gemm1_mfma(
    const ushort* __restrict__ A, const ushort* __restrict__ BT,
    const float* __restrict__ bias, ushort* __restrict__ h) {
    __shared__ ushort As[2][128 * 64];
    __shared__ ushort Bs[2][128 * 64];
    int tid = threadIdx.x;
    int wave = tid >> 6, lane = tid & 63;
    int wm = wave >> 1, wn = wave & 1;
    // bijective XCD swizzle (m204): nwg=1564, q=195, r=4
    int nwg = gridDim.x;
    int q = nwg >> 3, r = nwg & 7;
    int xcd = blockIdx.x & 7, pos = blockIdx.x >> 3;
    int base = (xcd < r) ? xcd * (q + 1) : r * (q + 1) + (xcd - r) * q;
    int id = base + pos;
    int row0 = (id >> 2) * 128;      // y-fastest: ids 4a..4a+3 share A-panel a
    int col0 = (id & 3) * 128;

    f32x4 acc[4][4] = {};

    auto stage = [&](int buf, int kk) {
        #pragma unroll
        for (int c = 0; c < 4; ++c) {
            int ch = wave + c * 4;
            int o = ch * 1024 + lane * 16;
            int row = o >> 7;
            int s = (o >> 4) & 7;
            int ssrc = s ^ (row & 7);
            int gr = row0 + row; if (gr > N_NODES - 1) gr = N_NODES - 1;
            gload_lds16(A + (size_t)gr * 256 + kk + (ssrc << 3), As[buf] + ch * 512);
            int gc = col0 + row;
            gload_lds16(BT + (size_t)gc * 256 + kk + (ssrc << 3), Bs[buf] + ch * 512);
        }
    };

    stage(0, 0);
    __syncthreads();
    #pragma unroll
    for (int t = 0; t < 4; ++t) {
        int cur = t & 1;
        if (t < 3) stage(cur ^ 1, (t + 1) * 64);   // issue next tile BEFORE compute
        #pragma unroll
        for (int kc = 0; kc < 2; ++kc) {
            int sbase = kc * 4 + (lane >> 4);
            bf16x8 af[4], bfr[4];
            #pragma unroll
            for (int m = 0; m < 4; ++m) {
                int row = wm * 64 + m * 16 + (lane & 15);
                af[m] = *(const bf16x8*)(As[cur] + row * 64 + ((sbase ^ (row & 7)) << 3));
            }
            #pragma unroll
            for (int n = 0; n < 4; ++n) {
                int row = wn * 64 + n * 16 + (lane & 15);
                bfr[n] = *(const bf16x8*)(Bs[cur] + row * 64 + ((sbase ^ (row & 7)) << 3));
            }
            #pragma unroll
            for (int m = 0; m < 4; ++m)
                #pragma unroll
                for (int n = 0; n < 4; ++n)
                    acc[m][n] = __builtin_amdgcn_mfma_f32_16x16x32_bf16(af[m], bfr[n], acc[m][n], 0, 0, 0);
        }
        __syncthreads();   // drains vmcnt for next tile + protects dbuf reuse
    }
    #pragma unroll
    for (int m = 0; m < 4; ++m) {
        #pragma unroll
        for (int j = 0; j < 4; ++j) {
            int grow = row0 + wm * 64 + m * 16 + (lane >> 4) * 4 + j;
            if (grow >= N_NODES) continue;
            #pragma unroll
            for (int n = 0; n < 4; ++n) {
                int gcol = col0 + wn * 64 + n * 16 + (lane & 15);
                float v = acc[m][n][j] + bias[gcol];
                h[(size_t)grow * 512 + gcol] = f2bf(v > 0.f ? v : 0.f);
            }
        }
    }
}

// [p|r] = h @ wt2^T   h:[50000][512] bf16, wt2:[80][512] bf16 — 2-phase dbuf
__global__ __launch_bounds__(256) void gemm2_mfma(
    const ushort* __restrict__ hbf, const ushort* __restrict__ wt2,
    ushort* __restrict__ p, float* __restrict__ r) {
    __shared__ ushort As[2][128 * 64];
    __shared__ ushort Bs[2][80 * 64];
    int tid = threadIdx.x;
    int wave = tid >> 6, lane = tid & 63;
    int row0 = blockIdx.x * 128;
    f32x4 acc[2][5] = {};

    auto stage = [&](int buf, int kk) {
        #pragma unroll
        for (int c = 0; c < 4; ++c) {
            int ch = wave + c * 4;
            int o = ch * 1024 + lane * 16;
            int row = o >> 7;
            int s = (o >> 4) & 7;
            int ssrc = s ^ (row & 7);
            int gr = row0 + row; if (gr > N_NODES - 1) gr = N_NODES - 1;
            gload_lds16(hbf + (size_t)gr * 512 + kk + (ssrc << 3), As[buf] + ch * 512);
        }
        for (int ch = wave; ch < 10; ch += 4) {
            int o = ch * 1024 + lane * 16;
            int row = o >> 7;
            int s = (o >> 4) & 7;
            int ssrc = s ^ (row & 7);
            gload_lds16(wt2 + (size_t)row * 512 + kk + (ssrc << 3), Bs[buf] + ch * 512);
        }
    };

    stage(0, 0);
    __syncthreads();
    #pragma unroll
    for (int t = 0; t < 8; ++t) {
        int cur = t & 1;
        if (t < 7) stage(cur ^ 1, (t + 1) * 64);
        #pragma unroll
        for (int kc = 0; kc < 2; ++kc) {
            int sbase = kc * 4 + (lane >> 4);
            bf16x8 af[2], bfr[5];
            #pragma unroll
            for (int m = 0; m < 2; ++m) {
                int row = wave * 32 + m * 16 + (lane & 15);
                af[m] = *(const bf16x8*)(As[cur] + row * 64 + ((sbase ^ (row & 7)) << 3));
            }
            #pragma unroll
            for (int n = 0; n < 5; ++n) {
                int row = n * 16 + (lane & 15);
                bfr[n] = *(const bf16x8*)(Bs[cur] + row * 64 + ((sbase ^ (row & 7)) << 3));
            }
            #pragma unroll
            for (int m = 0; m < 2; ++m)
                #pragma unroll
                for (int n = 0; n < 5; ++n)
                    acc[m][n] = __builtin_amdgcn_mfma_f32_16x16x32_bf16(af[m], bfr[n], acc[m][n], 0, 0, 0);
        }
        __syncthreads();
    }
    #pragma unroll
    for (int m = 0; m < 2; ++m) {
        #pragma unroll
        for (int j = 0; j < 4; ++j) {
            int grow = row0 + wave * 32 + m * 16 + (lane >> 4) * 4 + j;
            if (grow >= N_NODES) continue;
            #pragma unroll
            for (int n = 0; n < 5; ++n) {
                int col = n * 16 + (lane & 15);
                float v = acc[m][n][j];
                if (col < 40) p[(size_t)grow * 40 + col] = f2bf(v);
                else          r[(size_t)grow * 40 + (col - 40)] = v;
            }
        }
    }
}

// out = log_softmax(mean_j p[src] + b2 + r)  one wave per node, lanes 0..39
__global__ void final_kernel(const ushort* __restrict__ p, const float* __restrict__ rr,
                             const float* __restrict__ b2,
                             const int* __restrict__ row_ptr, const int* __restrict__ csr_src,
                             float* __restrict__ out) {
    int wid = threadIdx.x >> 6;
    int lane = threadIdx.x & 63;
    int n = blockIdx.x * 4 + wid;
    if (n >= N_NODES) return;
    int beg = row_ptr[n], end = row_ptr[n + 1];
    float acc0 = 0.f, acc1 = 0.f, acc2 = 0.f, acc3 = 0.f;
    int e = beg;
    if (lane < OUT_DIM) {
        for (; e + 3 < end; e += 4) {
            int s0 = csr_src[e], s1 = csr_src[e + 1];
            int s2 = csr_src[e + 2], s3 = csr_src[e + 3];
            acc0 += bf2f(p[(size_t)s0 * OUT_DIM + lane]);
            acc1 += bf2f(p[(size_t)s1 * OUT_DIM + lane]);
            acc2 += bf2f(p[(size_t)s2 * OUT_DIM + lane]);
            acc3 += bf2f(p[(size_t)s3 * OUT_DIM + lane]);
        }
        for (; e < end; ++e)
            acc0 += bf2f(p[(size_t)csr_src[e] * OUT_DIM + lane]);
    }
    int d = end - beg; if (d < 1) d = 1;
    float inv = 1.0f / (float)d;
    float v = (lane < OUT_DIM)
                  ? ((acc0 + acc1 + acc2 + acc3) * inv + b2[lane] + rr[(size_t)n * OUT_DIM + lane])
                  : -INFINITY;
    float m = v;
    #pragma unroll
    for (int off = 32; off; off >>= 1) m = fmaxf(m, __shfl_xor(m, off));
    float ex = (lane < OUT_DIM) ? expf(v - m) : 0.f;
    float ssum = ex;
    #pragma unroll
    for (int off = 32; off; off >>= 1) ssum += __shfl_xor(ssum, off);
    if (lane < OUT_DIM) out[(size_t)n * OUT_DIM + lane] = (v - m) - logf(ssum);
}

extern "C" void kernel_launch(void* const* d_in, const int* in_sizes, int n_in,
                              void* d_out, int out_size, void* d_ws, size_t ws_size,
                              hipStream_t stream) {
    const float* x    = (const float*)d_in[0];
    const int*   edge = (const int*)d_in[1];
    const int*   srce = edge;
    const int*   dste = edge + N_EDGES;
    const float* w1l  = (const float*)d_in[2];
    const float* b1   = (const float*)d_in[3];
    const float* w1r  = (const float*)d_in[4];
    const float* w2l  = (const float*)d_in[5];
    const float* b2   = (const float*)d_in[6];
    const float* w2r  = (const float*)d_in[7];
    float* out = (float*)d_out;

    char* ws = (char*)d_ws;
    size_t off = 0;
    auto alloc = [&](size_t bytes) -> void* {
        void* ptr = ws + off;
        off = (off + bytes + 255) & ~(size_t)255;
        return ptr;
    };
    int* deg     = (int*)alloc((size_t)2 * N_NODES * 4);
    int* cursor  = deg + N_NODES;
    int* row_ptr = (int*)alloc((size_t)(N_NODES + 1) * 4);
    int* bsum    = (int*)alloc((size_t)NB_SCAN * 4);
    int* csr_src = (int*)alloc((size_t)N_EDGES * 4);
    ushort* abuf = (ushort*)alloc((size_t)N_NODES * 256 * 2);   // [agg|x] bf16
    ushort* wt   = (ushort*)alloc((size_t)512 * 256 * 2);       // [w1_l;w1_r]^T bf16
    ushort* wt2  = (ushort*)alloc((size_t)80 * 512 * 2);        // [w2_l|w2_r]^T bf16
    ushort* h    = (ushort*)alloc((size_t)N_NODES * HID * 2);   // h bf16
    ushort* p    = (ushort*)alloc((size_t)N_NODES * OUT_DIM * 2);  // p bf16
    float* rbuf  = (float*)alloc((size_t)N_NODES * OUT_DIM * 4);

    zero_ints<<<(2 * N_NODES + 255) / 256, 256, 0, stream>>>(deg, 2 * N_NODES);
    count_deg_part<<<NRANGE * NCHUNK, 256, 0, stream>>>(dste, deg);
    deg_block_sums<<<NB_SCAN, 256, 0, stream>>>(deg, bsum);
    scan_bsum<<<1, 256, 0, stream>>>(bsum);
    scan_fill<<<NB_SCAN, 256, 0, stream>>>(deg, bsum, row_ptr);
    fill_csr_part<<<NRANGE * NCHUNK, 256, 0, stream>>>(srce, dste, row_ptr, cursor, csr_src);
    cvt_x<<<(N_NODES * 32 + 255) / 256, 256, 0, stream>>>(x, abuf);
    cvt_weights<<<(512 * 256 + 80 * 512 + 255) / 256, 256, 0, stream>>>(w1l, w1r, w2l, w2r, wt, wt2);
    agg_x<<<(N_NODES + 3) / 4, 256, 0, stream>>>(row_ptr, csr_src, abuf);
    gemm1_mfma<<<4 * ((N_NODES + 127) / 128), 256, 0, stream>>>(abuf, wt, b1, h);
    gemm2_mfma<<<(N_NODES + 127) / 128, 256, 0, stream>>>(h, wt2, p, rbuf);
    final_kernel<<<(N_NODES + 3) / 4, 256, 0, stream>>>(p, rbuf, b2, row_ptr, csr_src, out);
}